// Round 13
// baseline (140.791 us; speedup 1.0000x reference)
//
#include <hip/hip_runtime.h>
#include <cstdint>
#include <cstddef>

typedef _Float16 f16;
typedef f16 f16x2 __attribute__((ext_vector_type(2)));
typedef f16 f16x8 __attribute__((ext_vector_type(8)));
typedef __fp16 hf16x2 __attribute__((ext_vector_type(2)));  // cvt_pkrtz return type
typedef float f32x4 __attribute__((ext_vector_type(4)));
typedef float f32x16 __attribute__((ext_vector_type(16)));
typedef unsigned int u32;

#define S_LEN 2048
#define DIM 1024
#define NBATCH 2
#define NHEAD 16
#define HDIM 64
#define M_TOT (NBATCH * S_LEN)  // 4096

// Q scale folds 1/sqrt(Hd) AND log2(e) so softmax uses exp2 directly.
#define QSCALE 0.18033688011112042f  // 0.125 * 1.4426950408889634

// ---- workspace layout (bytes) ----
#define OFF_XQ 0ull
#define OFF_XK (OFF_XQ + (size_t)M_TOT * DIM * 2)
#define OFF_XV (OFF_XK + (size_t)M_TOT * DIM * 2)
#define OFF_WT (OFF_XV + (size_t)M_TOT * DIM * 2)          // 4 mats, [N][K] f16
#define OFF_Q  (OFF_WT + 4ull * DIM * DIM * 2)             // fragment-native layouts
#define OFF_K  (OFF_Q + (size_t)M_TOT * DIM * 2)
#define OFF_VT (OFF_K + (size_t)M_TOT * DIM * 2)
#define OFF_AO (OFF_VT + (size_t)M_TOT * DIM * 2)

// ---------------- async global->LDS (width 16) ----------------
typedef const __attribute__((address_space(1))) void GVp;
typedef __attribute__((address_space(3))) void LVp;
__device__ __forceinline__ void gload16(const void* g, void* l) {
  __builtin_amdgcn_global_load_lds((GVp*)g, (LVp*)l, 16, 0, 0);
}

__device__ __forceinline__ float fast_exp2(float x) {
  float r;
  asm("v_exp_f32 %0, %1" : "=v"(r) : "v"(x));
  return r;
}

// ---------------- cast fp32 -> fp16, 8 elems/thread ----------------
__global__ __launch_bounds__(256) void cast_x_kernel(
    const float* __restrict__ q, const float* __restrict__ k, const float* __restrict__ v,
    f16* __restrict__ oq, f16* __restrict__ ok, f16* __restrict__ ov) {
  const float* src = blockIdx.y == 0 ? q : blockIdx.y == 1 ? k : v;
  f16* dst = blockIdx.y == 0 ? oq : blockIdx.y == 1 ? ok : ov;
  size_t i = ((size_t)blockIdx.x * 256 + threadIdx.x) * 8;
  float4 a = *(const float4*)(src + i);
  float4 b = *(const float4*)(src + i + 4);
  f16x8 o;
  o[0] = (f16)a.x; o[1] = (f16)a.y; o[2] = (f16)a.z; o[3] = (f16)a.w;
  o[4] = (f16)b.x; o[5] = (f16)b.y; o[6] = (f16)b.z; o[7] = (f16)b.w;
  *(f16x8*)(dst + i) = o;
}

// ---------------- W [K][N] fp32 -> Wt [N][K] fp16 ----------------
__global__ __launch_bounds__(256) void transpose_w_kernel(
    const float* __restrict__ Wq, const float* __restrict__ Wk,
    const float* __restrict__ Wv, const float* __restrict__ Wp,
    f16* __restrict__ out) {
  const float* W = blockIdx.z == 0 ? Wq : blockIdx.z == 1 ? Wk : blockIdx.z == 2 ? Wv : Wp;
  f16* Wt = out + (size_t)blockIdx.z * DIM * DIM;
  __shared__ f16 tile[64][72];
  const int kt = blockIdx.x * 64, nt = blockIdx.y * 64;
  const int t = threadIdx.x, r = t >> 2, c0 = (t & 3) * 16;
#pragma unroll
  for (int i = 0; i < 16; i += 4) {
    float4 vv = *(const float4*)(W + (size_t)(kt + r) * DIM + nt + c0 + i);
    tile[r][c0 + i + 0] = (f16)vv.x; tile[r][c0 + i + 1] = (f16)vv.y;
    tile[r][c0 + i + 2] = (f16)vv.z; tile[r][c0 + i + 3] = (f16)vv.w;
  }
  __syncthreads();
  f16x8 o0, o1;
#pragma unroll
  for (int i = 0; i < 8; ++i) { o0[i] = tile[c0 + i][r]; o1[i] = tile[c0 + 8 + i][r]; }
  *(f16x8*)(Wt + (size_t)(nt + r) * DIM + kt + c0) = o0;
  *(f16x8*)(Wt + (size_t)(nt + r) * DIM + kt + c0 + 8) = o1;
}

// ------- 128x128 f16 GEMM core, UNSWIZZLED (r10 baseline; linear source keeps -------
// ------- global_load_lds coalescing; known 8-way LDS read conflict accepted)  -------
__device__ __forceinline__ void gemm_core(const f16* __restrict__ A, const f16* __restrict__ B,
                                          char* lds, f32x4 acc[4][4]) {
  const int tid = threadIdx.x;
  const int wid = tid >> 6, lane = tid & 63;
  const int l15 = lane & 15, l4 = lane >> 4;
  const int wm = (wid >> 1) * 64, wn = (wid & 1) * 64;
  const int srow = tid >> 2;
  const int scol = (tid & 3) * 8;
  const f16* gA = A + (size_t)srow * DIM + scol;
  const f16* gB = B + (size_t)srow * DIM + scol;
  const int ldst = wid * 1024;

  gload16(gA,            lds + ldst);
  gload16(gA + 64 * DIM, lds + 4096 + ldst);
  gload16(gB,            lds + 8192 + ldst);
  gload16(gB + 64 * DIM, lds + 12288 + ldst);
  __syncthreads();

  for (int kt = 0; kt < DIM / 32; ++kt) {
    char* cur = lds + (kt & 1) * 16384;
    if (kt + 1 < DIM / 32) {
      char* nxt = lds + ((kt + 1) & 1) * 16384;
      const f16* ga = gA + (kt + 1) * 32;
      const f16* gb = gB + (kt + 1) * 32;
      gload16(ga,            nxt + ldst);
      gload16(ga + 64 * DIM, nxt + 4096 + ldst);
      gload16(gb,            nxt + 8192 + ldst);
      gload16(gb + 64 * DIM, nxt + 12288 + ldst);
    }
    f16x8 af[4], bf[4];
#pragma unroll
    for (int mt = 0; mt < 4; ++mt)
      af[mt] = *(const f16x8*)(cur + (wm + mt * 16 + l15) * 64 + l4 * 16);
#pragma unroll
    for (int nt = 0; nt < 4; ++nt)
      bf[nt] = *(const f16x8*)(cur + 8192 + (wn + nt * 16 + l15) * 64 + l4 * 16);
#pragma unroll
    for (int mt = 0; mt < 4; ++mt)
#pragma unroll
      for (int nt = 0; nt < 4; ++nt)
        acc[mt][nt] = __builtin_amdgcn_mfma_f32_16x16x32_f16(af[mt], bf[nt], acc[mt][nt], 0, 0, 0);
    __syncthreads();
  }
}

// ------- f16 GEMM core, T2-SWIZZLED (A/B experiment — used by outproj only) -------
__device__ __forceinline__ void gemm_core_sw(const f16* __restrict__ A, const f16* __restrict__ B,
                                             char* lds, f32x4 acc[4][4]) {
  const int tid = threadIdx.x;
  const int wid = tid >> 6, lane = tid & 63;
  const int l15 = lane & 15, l4 = lane >> 4;
  const int wm = (wid >> 1) * 64, wn = (wid & 1) * 64;
  const int rr = tid >> 2, cc = tid & 3;
  const int ccs = cc ^ ((rr >> 1) & 3);                    // pre-swizzled source slot
  const f16* gA = A + (size_t)rr * DIM + ccs * 8;
  const f16* gB = B + (size_t)rr * DIM + ccs * 8;
  const int ldst = wid * 1024;

  gload16(gA,            lds + ldst);
  gload16(gA + 64 * DIM, lds + 4096 + ldst);
  gload16(gB,            lds + 8192 + ldst);
  gload16(gB + 64 * DIM, lds + 12288 + ldst);
  __syncthreads();

  const int sw = (l15 >> 1) & 3;
  for (int kt = 0; kt < DIM / 32; ++kt) {
    char* cur = lds + (kt & 1) * 16384;
    if (kt + 1 < DIM / 32) {
      char* nxt = lds + ((kt + 1) & 1) * 16384;
      const f16* ga = gA + (kt + 1) * 32;
      const f16* gb = gB + (kt + 1) * 32;
      gload16(ga,            nxt + ldst);
      gload16(ga + 64 * DIM, nxt + 4096 + ldst);
      gload16(gb,            nxt + 8192 + ldst);
      gload16(gb + 64 * DIM, nxt + 12288 + ldst);
    }
    f16x8 af[4], bf[4];
#pragma unroll
    for (int mt = 0; mt < 4; ++mt)
      af[mt] = *(const f16x8*)(cur + (wm + mt * 16 + l15) * 64 + (l4 ^ sw) * 16);
#pragma unroll
    for (int nt = 0; nt < 4; ++nt)
      bf[nt] = *(const f16x8*)(cur + 8192 + (wn + nt * 16 + l15) * 64 + (l4 ^ sw) * 16);
#pragma unroll
    for (int mt = 0; mt < 4; ++mt)
#pragma unroll
      for (int nt = 0; nt < 4; ++nt)
        acc[mt][nt] = __builtin_amdgcn_mfma_f32_16x16x32_f16(af[mt], bf[nt], acc[mt][nt], 0, 0, 0);
    __syncthreads();
  }
}

// Fragment-native addresses (elements) within one (batch,head) panel:
//  Q/K: tile32 = s>>5 ; addr = tile32*2048 + (d>>4)*512 + ((d>>3)&1)*256 + (s&31)*8 + (d&7)
//  V:   tile64 = s>>6 ; addr = tile64*4096 + (d>>5)*2048 + ((s>>4)&3)*512 + ((s>>3)&1)*256 + (d&31)*8 + (s&7)

// ---------------- batched QKV projection (f16 inputs; r10 baseline) ----------------
__global__ __launch_bounds__(256) void proj_kernel(
    const f16* __restrict__ Xq, const f16* __restrict__ Xk, const f16* __restrict__ Xv,
    const f16* __restrict__ Wt,
    const float* __restrict__ bq, const float* __restrict__ bk, const float* __restrict__ bv,
    f16* __restrict__ Q, f16* __restrict__ Kh, f16* __restrict__ Vt) {
  __shared__ __align__(16) char lds[32768];
  const int m0 = blockIdx.x * 128, n0 = blockIdx.y * 128;
  const int z = blockIdx.z;
  const f16* X = z == 0 ? Xq : z == 1 ? Xk : Xv;
  const f16* W = Wt + (size_t)z * DIM * DIM;
  const float* bias = z == 0 ? bq : z == 1 ? bk : bv;
  f32x4 acc[4][4] = {};
  gemm_core(X + (size_t)m0 * DIM, W + (size_t)n0 * DIM, lds, acc);

  const int tid = threadIdx.x, wid = tid >> 6, lane = tid & 63;
  const int l15 = lane & 15, l4 = lane >> 4;
  const int wm = (wid >> 1) * 64, wn = (wid & 1) * 64;
#pragma unroll
  for (int nt = 0; nt < 4; ++nt) {
    const int col = n0 + wn + nt * 16 + l15;
    const float bb = bias[col];
    const int hh = col >> 6, d = col & 63;
#pragma unroll
    for (int mt = 0; mt < 4; ++mt)
#pragma unroll
      for (int j = 0; j < 4; ++j) {
        const int row = m0 + wm + mt * 16 + l4 * 4 + j;
        const float v = acc[mt][nt][j] + bb;
        const int n = row >> 11, s = row & (S_LEN - 1);
        const size_t panel = (size_t)(n * NHEAD + hh);
        if (z == 0) {
          const size_t a = panel * (S_LEN * HDIM) + (size_t)(s >> 5) * 2048 +
                           (d >> 4) * 512 + ((d >> 3) & 1) * 256 + (s & 31) * 8 + (d & 7);
          Q[a] = (f16)(v * QSCALE);
        } else if (z == 1) {
          const size_t a = panel * (S_LEN * HDIM) + (size_t)(s >> 5) * 2048 +
                           (d >> 4) * 512 + ((d >> 3) & 1) * 256 + (s & 31) * 8 + (d & 7);
          Kh[a] = (f16)v;
        } else {
          const size_t a = panel * (S_LEN * HDIM) + (size_t)(s >> 6) * 4096 +
                           (d >> 5) * 2048 + ((s >> 4) & 3) * 512 + ((s >> 3) & 1) * 256 +
                           (d & 31) * 8 + (s & 7);
          Vt[a] = (f16)v;
        }
      }
  }
}

// ---------------- output projection -> fp32 d_out (SWIZZLED core: A/B experiment) --------
__global__ __launch_bounds__(256) void outproj_kernel(
    const f16* __restrict__ A, const f16* __restrict__ Wt,
    const float* __restrict__ bias, float* __restrict__ Out) {
  __shared__ __align__(16) char lds[32768];
  const int m0 = blockIdx.x * 128, n0 = blockIdx.y * 128;
  f32x4 acc[4][4] = {};
  gemm_core_sw(A + (size_t)m0 * DIM, Wt + (size_t)n0 * DIM, lds, acc);

  const int tid = threadIdx.x, wid = tid >> 6, lane = tid & 63;
  const int l15 = lane & 15, l4 = lane >> 4;
  const int wm = (wid >> 1) * 64, wn = (wid & 1) * 64;
#pragma unroll
  for (int nt = 0; nt < 4; ++nt) {
    const int col = n0 + wn + nt * 16 + l15;
    const float bb = bias[col];
#pragma unroll
    for (int mt = 0; mt < 4; ++mt)
#pragma unroll
      for (int j = 0; j < 4; ++j) {
        const int row = m0 + wm + mt * 16 + l4 * 4 + j;
        Out[(size_t)row * DIM + col] = acc[mt][nt][j] + bb;
      }
  }
}

// -------- flash attention: barrier-free 2-wave KV-split blocks, 32x32 MFMA --------
// Grid (S/32, H, N) = 2048 blocks of 128 thr; 4 free-running waves/SIMD; max-free
// softmax; halves combine by pure SUM via one LDS exchange + single barrier.
__global__ __launch_bounds__(128) void attn_kernel(
    const f16* __restrict__ Q, const f16* __restrict__ K,
    const f16* __restrict__ Vt, f16* __restrict__ AO) {
  const int qt = blockIdx.x, h = blockIdx.y, b = blockIdx.z;
  const int tid = threadIdx.x;
  const int lane = tid & 63, half = tid >> 6;   // wave = kv-half
  const int l31 = lane & 31, hi = lane >> 5;

  __shared__ float comb[2048 + 64];             // accO exchange (8KB) + l exchange

  const int q0 = qt * 32;
  const size_t panel = (size_t)(b * NHEAD + h) * (S_LEN * HDIM);
  const f16* Qp = Q + panel + (size_t)(q0 >> 5) * 2048;
  const f16* Kp = K + panel;
  const f16* Vp = Vt + panel;

  // Q as B-operand: col=q=l31, k-dim d = sk*16 + hi*8 + e
  f16x8 qf[4];
#pragma unroll
  for (int sk = 0; sk < 4; ++sk)
    qf[sk] = *(const f16x8*)(Qp + sk * 512 + hi * 256 + l31 * 8);

  f32x16 accO[2] = {};            // O^T[d][q]: dt in {0,1}, col=q=l31
  float lacc0 = 0.f, lacc1 = 0.f, lacc2 = 0.f, lacc3 = 0.f;  // 4-way l partial sums

  auto LOADK = [&](int it, f16x8 (&kf)[2][4]) {
#pragma unroll
    for (int tt = 0; tt < 2; ++tt)
#pragma unroll
      for (int sk = 0; sk < 4; ++sk)
        kf[tt][sk] = *(const f16x8*)(Kp + (size_t)(it * 2 + tt) * 2048 + sk * 512 + hi * 256 + l31 * 8);
  };
  auto LOADV = [&](int it, f16x8 (&vf)[2][4]) {
#pragma unroll
    for (int dt = 0; dt < 2; ++dt)
#pragma unroll
      for (int s = 0; s < 4; ++s)
        vf[dt][s] = *(const f16x8*)(Vp + (size_t)it * 4096 + dt * 2048 + s * 512 + hi * 256 + l31 * 8);
  };
  auto QK = [&](const f16x8 (&kf)[2][4], f32x16 (&st)[2]) {
    __builtin_amdgcn_s_setprio(1);
#pragma unroll
    for (int tt = 0; tt < 2; ++tt) {
      st[tt] = (f32x16)(0.f);
#pragma unroll
      for (int sk = 0; sk < 4; ++sk)
        st[tt] = __builtin_amdgcn_mfma_f32_32x32x16_f16(kf[tt][sk], qf[sk], st[tt], 0, 0, 0);
    }
    __builtin_amdgcn_s_setprio(0);
  };

  // exp2 + pack + l-accumulate + PV; fully per-lane, branch-free
  auto PHASE = [&](f32x16 (&st)[2], const f16x8 (&vf)[2][4]) {
    u32 pk[2][8];
#pragma unroll
    for (int tt = 0; tt < 2; ++tt)
#pragma unroll
      for (int j = 0; j < 8; ++j) {
        const float p0 = fast_exp2(st[tt][2 * j]);
        const float p1 = fast_exp2(st[tt][2 * j + 1]);
        const float ps = p0 + p1;
        if (((tt * 8 + j) & 3) == 0) lacc0 += ps;
        else if (((tt * 8 + j) & 3) == 1) lacc1 += ps;
        else if (((tt * 8 + j) & 3) == 2) lacc2 += ps;
        else lacc3 += ps;
        union { hf16x2 h; u32 w; } cv;
        cv.h = __builtin_amdgcn_cvt_pkrtz(p0, p1);
        pk[tt][j] = cv.w;
      }

    __builtin_amdgcn_s_setprio(1);
#pragma unroll
    for (int s = 0; s < 4; ++s) {
      const int tt = s >> 1, sl = s & 1;
      u32 w0 = pk[tt][4 * sl + 0], w2 = pk[tt][4 * sl + 2];
      u32 w1 = pk[tt][4 * sl + 1], w3 = pk[tt][4 * sl + 3];
      // swap: lanes>=32 of first arg <-> lanes<32 of second arg
      asm("v_permlane32_swap_b32 %0, %1" : "+v"(w0), "+v"(w2));
      asm("v_permlane32_swap_b32 %0, %1" : "+v"(w1), "+v"(w3));
      union { u32 w[4]; f16x8 v; } pf;
      pf.w[0] = w0; pf.w[1] = w1; pf.w[2] = w2; pf.w[3] = w3;
      accO[0] = __builtin_amdgcn_mfma_f32_32x32x16_f16(vf[0][s], pf.v, accO[0], 0, 0, 0);
      accO[1] = __builtin_amdgcn_mfma_f32_32x32x16_f16(vf[1][s], pf.v, accO[1], 0, 0, 0);
    }
    __builtin_amdgcn_s_setprio(0);
  };

  const int i0 = half * 16;    // this wave's kv-tile range: [i0, i0+16)

  f16x8 kfA[2][4], kfB[2][4], vfA[2][4], vfB[2][4];
  f32x16 st[2];
  LOADK(i0, kfA); LOADV(i0, vfA);
  LOADK(i0 + 1, kfB); LOADV(i0 + 1, vfB);
  QK(kfA, st);

  for (int it = i0; it < i0 + 14; it += 2) {
    PHASE(st, vfA);          // it
    LOADV(it + 2, vfA);
    QK(kfB, st);             // scores it+1
    LOADK(it + 2, kfA);
    PHASE(st, vfB);          // it+1
    LOADV(it + 3, vfB);
    QK(kfA, st);             // scores it+2
    LOADK(it + 3, kfB);
  }
  PHASE(st, vfA);            // i0+14
  QK(kfB, st);
  PHASE(st, vfB);            // i0+15

  // ---- combine halves: pure sums (max-free). One barrier in the whole kernel. ----
  const float l_loc = (lacc0 + lacc1) + (lacc2 + lacc3);
  if (half == 1) {
#pragma unroll
    for (int dt = 0; dt < 2; ++dt)
#pragma unroll
      for (int j = 0; j < 16; ++j)
        comb[(dt * 16 + j) * 64 + lane] = accO[dt][j];
    comb[2048 + lane] = l_loc;
  }
  __syncthreads();
  if (half == 0) {
#pragma unroll
    for (int dt = 0; dt < 2; ++dt)
#pragma unroll
      for (int j = 0; j < 16; ++j)
        accO[dt][j] += comb[(dt * 16 + j) * 64 + lane];
    const float l2 = l_loc + comb[2048 + lane];
    const float l_all = l2 + __shfl_xor(l2, 32);
    const float inv = 1.f / l_all;
    f16* aop = AO + ((size_t)(b * S_LEN + q0 + l31)) * DIM + h * HDIM;
#pragma unroll
    for (int dt = 0; dt < 2; ++dt)
#pragma unroll
      for (int j = 0; j < 8; ++j) {
        union { f16x2 h; u32 w; } cv;
        cv.h[0] = (f16)(accO[dt][2 * j] * inv);
        cv.h[1] = (f16)(accO[dt][2 * j + 1] * inv);
        const int d = ((2 * j) & 3) + 8 * ((2 * j) >> 2) + 4 * hi + dt * 32;
        *(f16x2*)(aop + d) = cv.h;
      }
  }
}

extern "C" void kernel_launch(void* const* d_in, const int* in_sizes, int n_in,
                              void* d_out, int out_size, void* d_ws, size_t ws_size,
                              hipStream_t stream) {
  (void)in_sizes; (void)n_in; (void)out_size; (void)ws_size;
  const float* q  = (const float*)d_in[0];
  const float* k  = (const float*)d_in[1];
  const float* v  = (const float*)d_in[2];
  const float* Wq = (const float*)d_in[3];
  const float* bq = (const float*)d_in[4];
  const float* Wk = (const float*)d_in[5];
  const float* bk = (const float*)d_in[6];
  const float* Wv = (const float*)d_in[7];
  const float* bv = (const float*)d_in[8];
  const float* Wp = (const float*)d_in[9];
  const float* bp = (const float*)d_in[10];

  char* ws = (char*)d_ws;
  f16* Xq  = (f16*)(ws + OFF_XQ);
  f16* Xk  = (f16*)(ws + OFF_XK);
  f16* Xv  = (f16*)(ws + OFF_XV);
  f16* Wt  = (f16*)(ws + OFF_WT);
  f16* Qs  = (f16*)(ws + OFF_Q);
  f16* Kh  = (f16*)(ws + OFF_K);
  f16* Vts = (f16*)(ws + OFF_VT);
  f16* AO  = (f16*)(ws + OFF_AO);

  cast_x_kernel<<<dim3(2048, 3, 1), 256, 0, stream>>>(q, k, v, Xq, Xk, Xv);
  transpose_w_kernel<<<dim3(16, 16, 4), 256, 0, stream>>>(Wq, Wk, Wv, Wp, Wt);
  proj_kernel<<<dim3(32, 8, 3), 256, 0, stream>>>(Xq, Xk, Xv, Wt, bq, bk, bv, Qs, Kh, Vts);
  attn_kernel<<<dim3(64, 16, 2), 128, 0, stream>>>(Qs, Kh, Vts, AO);
  outproj_kernel<<<dim3(32, 8, 1), 256, 0, stream>>>(AO, Wt + 3ull * DIM * DIM, bp, (float*)d_out);
}

// Round 14
// 140.457 us; speedup vs baseline: 1.0024x; 1.0024x over previous
//
#include <hip/hip_runtime.h>
#include <cstdint>
#include <cstddef>

typedef _Float16 f16;
typedef f16 f16x2 __attribute__((ext_vector_type(2)));
typedef f16 f16x8 __attribute__((ext_vector_type(8)));
typedef __fp16 hf16x2 __attribute__((ext_vector_type(2)));  // cvt_pkrtz return type
typedef float f32x4 __attribute__((ext_vector_type(4)));
typedef float f32x16 __attribute__((ext_vector_type(16)));
typedef unsigned int u32;

#define S_LEN 2048
#define DIM 1024
#define NBATCH 2
#define NHEAD 16
#define HDIM 64
#define M_TOT (NBATCH * S_LEN)  // 4096

// Q scale folds 1/sqrt(Hd) AND log2(e) so softmax uses exp2 directly.
#define QSCALE 0.18033688011112042f  // 0.125 * 1.4426950408889634

// ---- workspace layout (bytes) ----
#define OFF_XQ 0ull
#define OFF_XK (OFF_XQ + (size_t)M_TOT * DIM * 2)
#define OFF_XV (OFF_XK + (size_t)M_TOT * DIM * 2)
#define OFF_WT (OFF_XV + (size_t)M_TOT * DIM * 2)          // 4 mats, [N][K] f16
#define OFF_Q  (OFF_WT + 4ull * DIM * DIM * 2)             // fragment-native layouts
#define OFF_K  (OFF_Q + (size_t)M_TOT * DIM * 2)
#define OFF_VT (OFF_K + (size_t)M_TOT * DIM * 2)
#define OFF_AO (OFF_VT + (size_t)M_TOT * DIM * 2)
// attn partials REUSE the X regions (X dead after proj):
//   partO (f16, [half][b][h][q][d], 16 MB) at OFF_XQ ; partL (f32) at OFF_XV

// ---------------- async global->LDS (width 16) ----------------
typedef const __attribute__((address_space(1))) void GVp;
typedef __attribute__((address_space(3))) void LVp;
__device__ __forceinline__ void gload16(const void* g, void* l) {
  __builtin_amdgcn_global_load_lds((GVp*)g, (LVp*)l, 16, 0, 0);
}

__device__ __forceinline__ float fast_exp2(float x) {
  float r;
  asm("v_exp_f32 %0, %1" : "=v"(r) : "v"(x));
  return r;
}

// ---------------- cast fp32 -> fp16, 8 elems/thread ----------------
__global__ __launch_bounds__(256) void cast_x_kernel(
    const float* __restrict__ q, const float* __restrict__ k, const float* __restrict__ v,
    f16* __restrict__ oq, f16* __restrict__ ok, f16* __restrict__ ov) {
  const float* src = blockIdx.y == 0 ? q : blockIdx.y == 1 ? k : v;
  f16* dst = blockIdx.y == 0 ? oq : blockIdx.y == 1 ? ok : ov;
  size_t i = ((size_t)blockIdx.x * 256 + threadIdx.x) * 8;
  float4 a = *(const float4*)(src + i);
  float4 b = *(const float4*)(src + i + 4);
  f16x8 o;
  o[0] = (f16)a.x; o[1] = (f16)a.y; o[2] = (f16)a.z; o[3] = (f16)a.w;
  o[4] = (f16)b.x; o[5] = (f16)b.y; o[6] = (f16)b.z; o[7] = (f16)b.w;
  *(f16x8*)(dst + i) = o;
}

// ---------------- W [K][N] fp32 -> Wt [N][K] fp16 ----------------
__global__ __launch_bounds__(256) void transpose_w_kernel(
    const float* __restrict__ Wq, const float* __restrict__ Wk,
    const float* __restrict__ Wv, const float* __restrict__ Wp,
    f16* __restrict__ out) {
  const float* W = blockIdx.z == 0 ? Wq : blockIdx.z == 1 ? Wk : blockIdx.z == 2 ? Wv : Wp;
  f16* Wt = out + (size_t)blockIdx.z * DIM * DIM;
  __shared__ f16 tile[64][72];
  const int kt = blockIdx.x * 64, nt = blockIdx.y * 64;
  const int t = threadIdx.x, r = t >> 2, c0 = (t & 3) * 16;
#pragma unroll
  for (int i = 0; i < 16; i += 4) {
    float4 vv = *(const float4*)(W + (size_t)(kt + r) * DIM + nt + c0 + i);
    tile[r][c0 + i + 0] = (f16)vv.x; tile[r][c0 + i + 1] = (f16)vv.y;
    tile[r][c0 + i + 2] = (f16)vv.z; tile[r][c0 + i + 3] = (f16)vv.w;
  }
  __syncthreads();
  f16x8 o0, o1;
#pragma unroll
  for (int i = 0; i < 8; ++i) { o0[i] = tile[c0 + i][r]; o1[i] = tile[c0 + 8 + i][r]; }
  *(f16x8*)(Wt + (size_t)(nt + r) * DIM + kt + c0) = o0;
  *(f16x8*)(Wt + (size_t)(nt + r) * DIM + kt + c0 + 8) = o1;
}

// ------- 128x128 f16 GEMM core, T2-swizzled LDS (r13 A/B: not harmful, fixes 8-way) -------
__device__ __forceinline__ void gemm_core_sw(const f16* __restrict__ A, const f16* __restrict__ B,
                                             char* lds, f32x4 acc[4][4]) {
  const int tid = threadIdx.x;
  const int wid = tid >> 6, lane = tid & 63;
  const int l15 = lane & 15, l4 = lane >> 4;
  const int wm = (wid >> 1) * 64, wn = (wid & 1) * 64;
  const int rr = tid >> 2, cc = tid & 3;
  const int ccs = cc ^ ((rr >> 1) & 3);                    // pre-swizzled source slot
  const f16* gA = A + (size_t)rr * DIM + ccs * 8;
  const f16* gB = B + (size_t)rr * DIM + ccs * 8;
  const int ldst = wid * 1024;

  gload16(gA,            lds + ldst);
  gload16(gA + 64 * DIM, lds + 4096 + ldst);
  gload16(gB,            lds + 8192 + ldst);
  gload16(gB + 64 * DIM, lds + 12288 + ldst);
  __syncthreads();

  const int sw = (l15 >> 1) & 3;
  for (int kt = 0; kt < DIM / 32; ++kt) {
    char* cur = lds + (kt & 1) * 16384;
    if (kt + 1 < DIM / 32) {
      char* nxt = lds + ((kt + 1) & 1) * 16384;
      const f16* ga = gA + (kt + 1) * 32;
      const f16* gb = gB + (kt + 1) * 32;
      gload16(ga,            nxt + ldst);
      gload16(ga + 64 * DIM, nxt + 4096 + ldst);
      gload16(gb,            nxt + 8192 + ldst);
      gload16(gb + 64 * DIM, nxt + 12288 + ldst);
    }
    f16x8 af[4], bf[4];
#pragma unroll
    for (int mt = 0; mt < 4; ++mt)
      af[mt] = *(const f16x8*)(cur + (wm + mt * 16 + l15) * 64 + (l4 ^ sw) * 16);
#pragma unroll
    for (int nt = 0; nt < 4; ++nt)
      bf[nt] = *(const f16x8*)(cur + 8192 + (wn + nt * 16 + l15) * 64 + (l4 ^ sw) * 16);
#pragma unroll
    for (int mt = 0; mt < 4; ++mt)
#pragma unroll
      for (int nt = 0; nt < 4; ++nt)
        acc[mt][nt] = __builtin_amdgcn_mfma_f32_16x16x32_f16(af[mt], bf[nt], acc[mt][nt], 0, 0, 0);
    __syncthreads();
  }
}

// Fragment-native addresses (elements) within one (batch,head) panel:
//  Q/K: tile32 = s>>5 ; addr = tile32*2048 + (d>>4)*512 + ((d>>3)&1)*256 + (s&31)*8 + (d&7)
//  V:   tile64 = s>>6 ; addr = tile64*4096 + (d>>5)*2048 + ((s>>4)&3)*512 + ((s>>3)&1)*256 + (d&31)*8 + (s&7)

// ---------------- batched QKV projection (f16 inputs) ----------------
__global__ __launch_bounds__(256) void proj_kernel(
    const f16* __restrict__ Xq, const f16* __restrict__ Xk, const f16* __restrict__ Xv,
    const f16* __restrict__ Wt,
    const float* __restrict__ bq, const float* __restrict__ bk, const float* __restrict__ bv,
    f16* __restrict__ Q, f16* __restrict__ Kh, f16* __restrict__ Vt) {
  __shared__ __align__(16) char lds[32768];
  const int m0 = blockIdx.x * 128, n0 = blockIdx.y * 128;
  const int z = blockIdx.z;
  const f16* X = z == 0 ? Xq : z == 1 ? Xk : Xv;
  const f16* W = Wt + (size_t)z * DIM * DIM;
  const float* bias = z == 0 ? bq : z == 1 ? bk : bv;
  f32x4 acc[4][4] = {};
  gemm_core_sw(X + (size_t)m0 * DIM, W + (size_t)n0 * DIM, lds, acc);

  const int tid = threadIdx.x, wid = tid >> 6, lane = tid & 63;
  const int l15 = lane & 15, l4 = lane >> 4;
  const int wm = (wid >> 1) * 64, wn = (wid & 1) * 64;
#pragma unroll
  for (int nt = 0; nt < 4; ++nt) {
    const int col = n0 + wn + nt * 16 + l15;
    const float bb = bias[col];
    const int hh = col >> 6, d = col & 63;
#pragma unroll
    for (int mt = 0; mt < 4; ++mt)
#pragma unroll
      for (int j = 0; j < 4; ++j) {
        const int row = m0 + wm + mt * 16 + l4 * 4 + j;
        const float v = acc[mt][nt][j] + bb;
        const int n = row >> 11, s = row & (S_LEN - 1);
        const size_t panel = (size_t)(n * NHEAD + hh);
        if (z == 0) {
          const size_t a = panel * (S_LEN * HDIM) + (size_t)(s >> 5) * 2048 +
                           (d >> 4) * 512 + ((d >> 3) & 1) * 256 + (s & 31) * 8 + (d & 7);
          Q[a] = (f16)(v * QSCALE);
        } else if (z == 1) {
          const size_t a = panel * (S_LEN * HDIM) + (size_t)(s >> 5) * 2048 +
                           (d >> 4) * 512 + ((d >> 3) & 1) * 256 + (s & 31) * 8 + (d & 7);
          Kh[a] = (f16)v;
        } else {
          const size_t a = panel * (S_LEN * HDIM) + (size_t)(s >> 6) * 4096 +
                           (d >> 5) * 2048 + ((s >> 4) & 3) * 512 + ((s >> 3) & 1) * 256 +
                           (d & 31) * 8 + (s & 7);
          Vt[a] = (f16)v;
        }
      }
  }
}

// ---------------- output projection -> fp32 d_out ----------------
__global__ __launch_bounds__(256) void outproj_kernel(
    const f16* __restrict__ A, const f16* __restrict__ Wt,
    const float* __restrict__ bias, float* __restrict__ Out) {
  __shared__ __align__(16) char lds[32768];
  const int m0 = blockIdx.x * 128, n0 = blockIdx.y * 128;
  f32x4 acc[4][4] = {};
  gemm_core_sw(A + (size_t)m0 * DIM, Wt + (size_t)n0 * DIM, lds, acc);

  const int tid = threadIdx.x, wid = tid >> 6, lane = tid & 63;
  const int l15 = lane & 15, l4 = lane >> 4;
  const int wm = (wid >> 1) * 64, wn = (wid & 1) * 64;
#pragma unroll
  for (int nt = 0; nt < 4; ++nt) {
    const int col = n0 + wn + nt * 16 + l15;
    const float bb = bias[col];
#pragma unroll
    for (int mt = 0; mt < 4; ++mt)
#pragma unroll
      for (int j = 0; j < 4; ++j) {
        const int row = m0 + wm + mt * 16 + l4 * 4 + j;
        Out[(size_t)row * DIM + col] = acc[mt][nt][j] + bb;
      }
  }
}

// -------- flash attention: KV-split ACROSS BLOCKS, LDS-staged, 32x32 MFMA --------
// Grid (S/128, H, N*2) = 1024 blocks of 256 thr -> 4 blocks/CU, 4 waves/SIMD of
// mutually independent (separately-barriered) waves. Each block: r7-proven staging
// loop over its 16 kv-tiles (half = blockIdx.z&1). Max-free softmax -> partials
// (unnormalized O as f16, l as f32) combine by pure SUM in a tiny second kernel.
__global__ __launch_bounds__(256, 4) void attn_kernel(
    const f16* __restrict__ Q, const f16* __restrict__ K,
    const f16* __restrict__ Vt, f16* __restrict__ partO, float* __restrict__ partL) {
  const int qt = blockIdx.x, h = blockIdx.y;
  const int b = blockIdx.z >> 1, half = blockIdx.z & 1;
  const int tid = threadIdx.x;
  const int lane = tid & 63, wid = tid >> 6;
  const int l31 = lane & 31, hi = lane >> 5;

  __shared__ __align__(16) char kv_lds[2][16384];  // [buf][K 8KB | V 8KB]

  const int q0 = qt * 128 + wid * 32;
  const size_t panel = (size_t)(b * NHEAD + h) * (S_LEN * HDIM);
  const f16* Qp = Q + panel + (size_t)(q0 >> 5) * 2048;
  const char* KpB = (const char*)(K + panel);
  const char* VpB = (const char*)(Vt + panel);

  // Q as B-operand: col=q=l31, k-dim d = sk*16 + hi*8 + e
  f16x8 qf[4];
#pragma unroll
  for (int sk = 0; sk < 4; ++sk)
    qf[sk] = *(const f16x8*)(Qp + sk * 512 + hi * 256 + l31 * 8);

  f32x16 accO[2] = {};            // O^T[d][q]: dt in {0,1}, col=q=l31
  float lacc0 = 0.f, lacc1 = 0.f, lacc2 = 0.f, lacc3 = 0.f;  // 4-way l partial sums

  const int NIT = 16;             // 16 kv-tiles per half

  auto STAGE = [&](int it, int buf) {
    const size_t gt = (size_t)(half * NIT + it) * 8192;
    const char* gK = KpB + gt + tid * 16;
    const char* gV = VpB + gt + tid * 16;
    char* lb = &kv_lds[buf][wid * 1024];             // wave-uniform dest (+lane*16 in HW)
    gload16(gK,        lb);
    gload16(gK + 4096, lb + 4096);
    gload16(gV,        lb + 8192);
    gload16(gV + 4096, lb + 12288);
  };

  auto QK = [&](int buf, f32x16 (&st)[2]) {
    const char* lk = &kv_lds[buf][0];
    f16x8 kf[2][4];
#pragma unroll
    for (int tt = 0; tt < 2; ++tt)
#pragma unroll
      for (int sk = 0; sk < 4; ++sk)
        kf[tt][sk] = *(const f16x8*)(lk + tt * 4096 + sk * 1024 + lane * 16);
    __builtin_amdgcn_s_setprio(1);
#pragma unroll
    for (int tt = 0; tt < 2; ++tt) {
      st[tt] = (f32x16)(0.f);
#pragma unroll
      for (int sk = 0; sk < 4; ++sk)
        st[tt] = __builtin_amdgcn_mfma_f32_32x32x16_f16(kf[tt][sk], qf[sk], st[tt], 0, 0, 0);
    }
    __builtin_amdgcn_s_setprio(0);
  };

  auto PHASE = [&](f32x16 (&st)[2], int buf) {
    const char* lv = &kv_lds[buf][8192];
    f16x8 vf[2][4];
#pragma unroll
    for (int dt = 0; dt < 2; ++dt)
#pragma unroll
      for (int s = 0; s < 4; ++s)
        vf[dt][s] = *(const f16x8*)(lv + dt * 4096 + s * 1024 + lane * 16);

    u32 pk[2][8];
#pragma unroll
    for (int tt = 0; tt < 2; ++tt)
#pragma unroll
      for (int j = 0; j < 8; ++j) {
        const float p0 = fast_exp2(st[tt][2 * j]);
        const float p1 = fast_exp2(st[tt][2 * j + 1]);
        const float ps = p0 + p1;
        if (((tt * 8 + j) & 3) == 0) lacc0 += ps;
        else if (((tt * 8 + j) & 3) == 1) lacc1 += ps;
        else if (((tt * 8 + j) & 3) == 2) lacc2 += ps;
        else lacc3 += ps;
        union { hf16x2 h; u32 w; } cv;
        cv.h = __builtin_amdgcn_cvt_pkrtz(p0, p1);
        pk[tt][j] = cv.w;
      }

    __builtin_amdgcn_s_setprio(1);
#pragma unroll
    for (int s = 0; s < 4; ++s) {
      const int tt = s >> 1, sl = s & 1;
      u32 w0 = pk[tt][4 * sl + 0], w2 = pk[tt][4 * sl + 2];
      u32 w1 = pk[tt][4 * sl + 1], w3 = pk[tt][4 * sl + 3];
      asm("v_permlane32_swap_b32 %0, %1" : "+v"(w0), "+v"(w2));
      asm("v_permlane32_swap_b32 %0, %1" : "+v"(w1), "+v"(w3));
      union { u32 w[4]; f16x8 v; } pf;
      pf.w[0] = w0; pf.w[1] = w1; pf.w[2] = w2; pf.w[3] = w3;
      accO[0] = __builtin_amdgcn_mfma_f32_32x32x16_f16(vf[0][s], pf.v, accO[0], 0, 0, 0);
      accO[1] = __builtin_amdgcn_mfma_f32_32x32x16_f16(vf[1][s], pf.v, accO[1], 0, 0, 0);
    }
    __builtin_amdgcn_s_setprio(0);
  };

  STAGE(0, 0);
  __syncthreads();

  f32x16 st[2];
  for (int it = 0; it < NIT; ++it) {
    const int buf = it & 1;
    if (it + 1 < NIT) STAGE(it + 1, buf ^ 1);
    QK(buf, st);
    PHASE(st, buf);
    __syncthreads();
  }

  // ---- write unnormalized partials (combine kernel sums the two halves) ----
  const float l_loc = (lacc0 + lacc1) + (lacc2 + lacc3);
  const float l_all = l_loc + __shfl_xor(l_loc, 32);   // sum over hi-halves of t
  const size_t pb = (((size_t)(half * NBATCH + b) * NHEAD + h) * S_LEN + q0 + l31) * HDIM;
#pragma unroll
  for (int dt = 0; dt < 2; ++dt)
#pragma unroll
    for (int j = 0; j < 8; ++j) {
      union { f16x2 h; u32 w; } cv;
      cv.h[0] = (f16)accO[dt][2 * j];
      cv.h[1] = (f16)accO[dt][2 * j + 1];
      const int d = ((2 * j) & 3) + 8 * ((2 * j) >> 2) + 4 * hi + dt * 32;
      *(f16x2*)(partO + pb + d) = cv.h;
    }
  if (hi == 0)
    partL[((size_t)(half * NBATCH + b) * NHEAD + h) * S_LEN + q0 + l31] = l_all;
}

// ---------------- combine halves: O = (O0+O1)/(l0+l1), write AO [b][s][h*64+d] --------
__global__ __launch_bounds__(256) void combine_kernel(
    const f16* __restrict__ partO, const float* __restrict__ partL, f16* __restrict__ AO) {
  const size_t idx = (size_t)blockIdx.x * 256 + threadIdx.x;
  const size_t e = idx * 8;                         // element index within [b][h][q][d]
  const int d0 = (int)(e & 63);
  const int q  = (int)((e >> 6) & (S_LEN - 1));
  const int h  = (int)((e >> 17) & (NHEAD - 1));
  const int b  = (int)(e >> 21);
  const size_t base = (((size_t)b * NHEAD + h) * S_LEN + q) * HDIM + d0;
  const size_t off1 = (size_t)NBATCH * NHEAD * S_LEN * HDIM;
  f16x8 a0 = *(const f16x8*)(partO + base);
  f16x8 a1 = *(const f16x8*)(partO + off1 + base);
  const size_t lb = ((size_t)b * NHEAD + h) * S_LEN + q;
  const float inv = 1.f / (partL[lb] + partL[(size_t)NBATCH * NHEAD * S_LEN + lb]);
  f16x8 o;
#pragma unroll
  for (int i = 0; i < 8; ++i)
    o[i] = (f16)(((float)a0[i] + (float)a1[i]) * inv);
  *(f16x8*)(AO + ((size_t)(b * S_LEN + q)) * DIM + h * HDIM + d0) = o;
}

extern "C" void kernel_launch(void* const* d_in, const int* in_sizes, int n_in,
                              void* d_out, int out_size, void* d_ws, size_t ws_size,
                              hipStream_t stream) {
  (void)in_sizes; (void)n_in; (void)out_size; (void)ws_size;
  const float* q  = (const float*)d_in[0];
  const float* k  = (const float*)d_in[1];
  const float* v  = (const float*)d_in[2];
  const float* Wq = (const float*)d_in[3];
  const float* bq = (const float*)d_in[4];
  const float* Wk = (const float*)d_in[5];
  const float* bk = (const float*)d_in[6];
  const float* Wv = (const float*)d_in[7];
  const float* bv = (const float*)d_in[8];
  const float* Wp = (const float*)d_in[9];
  const float* bp = (const float*)d_in[10];

  char* ws = (char*)d_ws;
  f16* Xq  = (f16*)(ws + OFF_XQ);
  f16* Xk  = (f16*)(ws + OFF_XK);
  f16* Xv  = (f16*)(ws + OFF_XV);
  f16* Wt  = (f16*)(ws + OFF_WT);
  f16* Qs  = (f16*)(ws + OFF_Q);
  f16* Kh  = (f16*)(ws + OFF_K);
  f16* Vts = (f16*)(ws + OFF_VT);
  f16* AO  = (f16*)(ws + OFF_AO);
  f16* partO = (f16*)(ws + OFF_XQ);   // 16 MB: spans XQ+XK (X dead after proj)
  float* partL = (float*)(ws + OFF_XV);

  cast_x_kernel<<<dim3(2048, 3, 1), 256, 0, stream>>>(q, k, v, Xq, Xk, Xv);
  transpose_w_kernel<<<dim3(16, 16, 4), 256, 0, stream>>>(Wq, Wk, Wv, Wp, Wt);
  proj_kernel<<<dim3(32, 8, 3), 256, 0, stream>>>(Xq, Xk, Xv, Wt, bq, bk, bv, Qs, Kh, Vts);
  attn_kernel<<<dim3(16, 16, 4), 256, 0, stream>>>(Qs, Kh, Vts, partO, partL);
  combine_kernel<<<dim3(2048, 1, 1), 256, 0, stream>>>(partO, partL, AO);
  outproj_kernel<<<dim3(32, 8, 1), 256, 0, stream>>>(AO, Wt + 3ull * DIM * DIM, bp, (float*)d_out);
}

// Round 15
// 128.805 us; speedup vs baseline: 1.0931x; 1.0905x over previous
//
#include <hip/hip_runtime.h>
#include <cstdint>
#include <cstddef>

typedef _Float16 f16;
typedef f16 f16x2 __attribute__((ext_vector_type(2)));
typedef f16 f16x8 __attribute__((ext_vector_type(8)));
typedef __fp16 hf16x2 __attribute__((ext_vector_type(2)));  // cvt_pkrtz return type
typedef float f32x4 __attribute__((ext_vector_type(4)));
typedef float f32x16 __attribute__((ext_vector_type(16)));
typedef unsigned int u32;

#define S_LEN 2048
#define DIM 1024
#define NBATCH 2
#define NHEAD 16
#define HDIM 64
#define M_TOT (NBATCH * S_LEN)  // 4096

// Q scale folds 1/sqrt(Hd) AND log2(e) so softmax uses exp2 directly.
#define QSCALE 0.18033688011112042f  // 0.125 * 1.4426950408889634

// ---- workspace layout (bytes) ----
#define OFF_XQ 0ull
#define OFF_XK (OFF_XQ + (size_t)M_TOT * DIM * 2)
#define OFF_XV (OFF_XK + (size_t)M_TOT * DIM * 2)
#define OFF_WT (OFF_XV + (size_t)M_TOT * DIM * 2)          // 4 mats, [N][K] f16
#define OFF_Q  (OFF_WT + 4ull * DIM * DIM * 2)             // fragment-native layouts
#define OFF_K  (OFF_Q + (size_t)M_TOT * DIM * 2)
#define OFF_VT (OFF_K + (size_t)M_TOT * DIM * 2)
#define OFF_AO (OFF_VT + (size_t)M_TOT * DIM * 2)

// ---------------- async global->LDS (width 16) ----------------
typedef const __attribute__((address_space(1))) void GVp;
typedef __attribute__((address_space(3))) void LVp;
__device__ __forceinline__ void gload16(const void* g, void* l) {
  __builtin_amdgcn_global_load_lds((GVp*)g, (LVp*)l, 16, 0, 0);
}

__device__ __forceinline__ float fast_exp2(float x) {
  float r;
  asm("v_exp_f32 %0, %1" : "=v"(r) : "v"(x));
  return r;
}

// ---------------- cast fp32 -> fp16, 8 elems/thread ----------------
__global__ __launch_bounds__(256) void cast_x_kernel(
    const float* __restrict__ q, const float* __restrict__ k, const float* __restrict__ v,
    f16* __restrict__ oq, f16* __restrict__ ok, f16* __restrict__ ov) {
  const float* src = blockIdx.y == 0 ? q : blockIdx.y == 1 ? k : v;
  f16* dst = blockIdx.y == 0 ? oq : blockIdx.y == 1 ? ok : ov;
  size_t i = ((size_t)blockIdx.x * 256 + threadIdx.x) * 8;
  float4 a = *(const float4*)(src + i);
  float4 b = *(const float4*)(src + i + 4);
  f16x8 o;
  o[0] = (f16)a.x; o[1] = (f16)a.y; o[2] = (f16)a.z; o[3] = (f16)a.w;
  o[4] = (f16)b.x; o[5] = (f16)b.y; o[6] = (f16)b.z; o[7] = (f16)b.w;
  *(f16x8*)(dst + i) = o;
}

// ---------------- W [K][N] fp32 -> Wt [N][K] fp16 ----------------
__global__ __launch_bounds__(256) void transpose_w_kernel(
    const float* __restrict__ Wq, const float* __restrict__ Wk,
    const float* __restrict__ Wv, const float* __restrict__ Wp,
    f16* __restrict__ out) {
  const float* W = blockIdx.z == 0 ? Wq : blockIdx.z == 1 ? Wk : blockIdx.z == 2 ? Wv : Wp;
  f16* Wt = out + (size_t)blockIdx.z * DIM * DIM;
  __shared__ f16 tile[64][72];
  const int kt = blockIdx.x * 64, nt = blockIdx.y * 64;
  const int t = threadIdx.x, r = t >> 2, c0 = (t & 3) * 16;
#pragma unroll
  for (int i = 0; i < 16; i += 4) {
    float4 vv = *(const float4*)(W + (size_t)(kt + r) * DIM + nt + c0 + i);
    tile[r][c0 + i + 0] = (f16)vv.x; tile[r][c0 + i + 1] = (f16)vv.y;
    tile[r][c0 + i + 2] = (f16)vv.z; tile[r][c0 + i + 3] = (f16)vv.w;
  }
  __syncthreads();
  f16x8 o0, o1;
#pragma unroll
  for (int i = 0; i < 8; ++i) { o0[i] = tile[c0 + i][r]; o1[i] = tile[c0 + 8 + i][r]; }
  *(f16x8*)(Wt + (size_t)(nt + r) * DIM + kt + c0) = o0;
  *(f16x8*)(Wt + (size_t)(nt + r) * DIM + kt + c0 + 8) = o1;
}

// ------- 128x128 f16 GEMM core, T2-swizzled LDS (r13-validated) -------
__device__ __forceinline__ void gemm_core_sw(const f16* __restrict__ A, const f16* __restrict__ B,
                                             char* lds, f32x4 acc[4][4]) {
  const int tid = threadIdx.x;
  const int wid = tid >> 6, lane = tid & 63;
  const int l15 = lane & 15, l4 = lane >> 4;
  const int wm = (wid >> 1) * 64, wn = (wid & 1) * 64;
  const int rr = tid >> 2, cc = tid & 3;
  const int ccs = cc ^ ((rr >> 1) & 3);                    // pre-swizzled source slot
  const f16* gA = A + (size_t)rr * DIM + ccs * 8;
  const f16* gB = B + (size_t)rr * DIM + ccs * 8;
  const int ldst = wid * 1024;

  gload16(gA,            lds + ldst);
  gload16(gA + 64 * DIM, lds + 4096 + ldst);
  gload16(gB,            lds + 8192 + ldst);
  gload16(gB + 64 * DIM, lds + 12288 + ldst);
  __syncthreads();

  const int sw = (l15 >> 1) & 3;
  for (int kt = 0; kt < DIM / 32; ++kt) {
    char* cur = lds + (kt & 1) * 16384;
    if (kt + 1 < DIM / 32) {
      char* nxt = lds + ((kt + 1) & 1) * 16384;
      const f16* ga = gA + (kt + 1) * 32;
      const f16* gb = gB + (kt + 1) * 32;
      gload16(ga,            nxt + ldst);
      gload16(ga + 64 * DIM, nxt + 4096 + ldst);
      gload16(gb,            nxt + 8192 + ldst);
      gload16(gb + 64 * DIM, nxt + 12288 + ldst);
    }
    f16x8 af[4], bf[4];
#pragma unroll
    for (int mt = 0; mt < 4; ++mt)
      af[mt] = *(const f16x8*)(cur + (wm + mt * 16 + l15) * 64 + (l4 ^ sw) * 16);
#pragma unroll
    for (int nt = 0; nt < 4; ++nt)
      bf[nt] = *(const f16x8*)(cur + 8192 + (wn + nt * 16 + l15) * 64 + (l4 ^ sw) * 16);
#pragma unroll
    for (int mt = 0; mt < 4; ++mt)
#pragma unroll
      for (int nt = 0; nt < 4; ++nt)
        acc[mt][nt] = __builtin_amdgcn_mfma_f32_16x16x32_f16(af[mt], bf[nt], acc[mt][nt], 0, 0, 0);
    __syncthreads();
  }
}

// Fragment-native addresses (elements) within one (batch,head) panel:
//  Q/K: tile32 = s>>5 ; addr = tile32*2048 + (d>>4)*512 + ((d>>3)&1)*256 + (s&31)*8 + (d&7)
//  V:   tile64 = s>>6 ; addr = tile64*4096 + (d>>5)*2048 + ((s>>4)&3)*512 + ((s>>3)&1)*256 + (d&31)*8 + (s&7)

// ---------------- batched QKV projection (f16 inputs) ----------------
__global__ __launch_bounds__(256) void proj_kernel(
    const f16* __restrict__ Xq, const f16* __restrict__ Xk, const f16* __restrict__ Xv,
    const f16* __restrict__ Wt,
    const float* __restrict__ bq, const float* __restrict__ bk, const float* __restrict__ bv,
    f16* __restrict__ Q, f16* __restrict__ Kh, f16* __restrict__ Vt) {
  __shared__ __align__(16) char lds[32768];
  const int m0 = blockIdx.x * 128, n0 = blockIdx.y * 128;
  const int z = blockIdx.z;
  const f16* X = z == 0 ? Xq : z == 1 ? Xk : Xv;
  const f16* W = Wt + (size_t)z * DIM * DIM;
  const float* bias = z == 0 ? bq : z == 1 ? bk : bv;
  f32x4 acc[4][4] = {};
  gemm_core_sw(X + (size_t)m0 * DIM, W + (size_t)n0 * DIM, lds, acc);

  const int tid = threadIdx.x, wid = tid >> 6, lane = tid & 63;
  const int l15 = lane & 15, l4 = lane >> 4;
  const int wm = (wid >> 1) * 64, wn = (wid & 1) * 64;
#pragma unroll
  for (int nt = 0; nt < 4; ++nt) {
    const int col = n0 + wn + nt * 16 + l15;
    const float bb = bias[col];
    const int hh = col >> 6, d = col & 63;
#pragma unroll
    for (int mt = 0; mt < 4; ++mt)
#pragma unroll
      for (int j = 0; j < 4; ++j) {
        const int row = m0 + wm + mt * 16 + l4 * 4 + j;
        const float v = acc[mt][nt][j] + bb;
        const int n = row >> 11, s = row & (S_LEN - 1);
        const size_t panel = (size_t)(n * NHEAD + hh);
        if (z == 0) {
          const size_t a = panel * (S_LEN * HDIM) + (size_t)(s >> 5) * 2048 +
                           (d >> 4) * 512 + ((d >> 3) & 1) * 256 + (s & 31) * 8 + (d & 7);
          Q[a] = (f16)(v * QSCALE);
        } else if (z == 1) {
          const size_t a = panel * (S_LEN * HDIM) + (size_t)(s >> 5) * 2048 +
                           (d >> 4) * 512 + ((d >> 3) & 1) * 256 + (s & 31) * 8 + (d & 7);
          Kh[a] = (f16)v;
        } else {
          const size_t a = panel * (S_LEN * HDIM) + (size_t)(s >> 6) * 4096 +
                           (d >> 5) * 2048 + ((s >> 4) & 3) * 512 + ((s >> 3) & 1) * 256 +
                           (d & 31) * 8 + (s & 7);
          Vt[a] = (f16)v;
        }
      }
  }
}

// ------- 64x128 f16 GEMM core (outproj): 512 blocks -> 2 blocks/CU -------
// 4 waves tile 64x128 as (wid>>1)*32 x (wid&1)*64; acc[2][4]; LDS 2 x (A 4KB + B 8KB).
__device__ __forceinline__ void gemm_core_sw64(const f16* __restrict__ A, const f16* __restrict__ B,
                                               char* lds, f32x4 acc[2][4]) {
  const int tid = threadIdx.x;
  const int wid = tid >> 6, lane = tid & 63;
  const int l15 = lane & 15, l4 = lane >> 4;
  const int wm = (wid >> 1) * 32, wn = (wid & 1) * 64;
  const int rr = tid >> 2, cc = tid & 3;
  const int ccs = cc ^ ((rr >> 1) & 3);                    // pre-swizzled source slot
  const f16* gA = A + (size_t)rr * DIM + ccs * 8;          // rows 0..63
  const f16* gB = B + (size_t)rr * DIM + ccs * 8;
  const int ldst = wid * 1024;

  // buf layout: [buf][A 4KB | B 8KB], buf stride 12KB
  gload16(gA,            lds + ldst);                      // A rows 0..63
  gload16(gB,            lds + 4096 + ldst);               // B rows 0..63
  gload16(gB + 64 * DIM, lds + 8192 + ldst);               // B rows 64..127
  __syncthreads();

  const int sw = (l15 >> 1) & 3;
  for (int kt = 0; kt < DIM / 32; ++kt) {
    char* cur = lds + (kt & 1) * 12288;
    if (kt + 1 < DIM / 32) {
      char* nxt = lds + ((kt + 1) & 1) * 12288;
      const f16* ga = gA + (kt + 1) * 32;
      const f16* gb = gB + (kt + 1) * 32;
      gload16(ga,            nxt + ldst);
      gload16(gb,            nxt + 4096 + ldst);
      gload16(gb + 64 * DIM, nxt + 8192 + ldst);
    }
    f16x8 af[2], bf[4];
#pragma unroll
    for (int mt = 0; mt < 2; ++mt)
      af[mt] = *(const f16x8*)(cur + (wm + mt * 16 + l15) * 64 + (l4 ^ sw) * 16);
#pragma unroll
    for (int nt = 0; nt < 4; ++nt)
      bf[nt] = *(const f16x8*)(cur + 4096 + (wn + nt * 16 + l15) * 64 + (l4 ^ sw) * 16);
#pragma unroll
    for (int mt = 0; mt < 2; ++mt)
#pragma unroll
      for (int nt = 0; nt < 4; ++nt)
        acc[mt][nt] = __builtin_amdgcn_mfma_f32_16x16x32_f16(af[mt], bf[nt], acc[mt][nt], 0, 0, 0);
    __syncthreads();
  }
}

// ---------------- output projection -> fp32 d_out (64-row tile, 2 blocks/CU) --------
__global__ __launch_bounds__(256) void outproj_kernel(
    const f16* __restrict__ A, const f16* __restrict__ Wt,
    const float* __restrict__ bias, float* __restrict__ Out) {
  __shared__ __align__(16) char lds[24576];
  const int m0 = blockIdx.x * 64, n0 = blockIdx.y * 128;
  f32x4 acc[2][4] = {};
  gemm_core_sw64(A + (size_t)m0 * DIM, Wt + (size_t)n0 * DIM, lds, acc);

  const int tid = threadIdx.x, wid = tid >> 6, lane = tid & 63;
  const int l15 = lane & 15, l4 = lane >> 4;
  const int wm = (wid >> 1) * 32, wn = (wid & 1) * 64;
#pragma unroll
  for (int nt = 0; nt < 4; ++nt) {
    const int col = n0 + wn + nt * 16 + l15;
    const float bb = bias[col];
#pragma unroll
    for (int mt = 0; mt < 2; ++mt)
#pragma unroll
      for (int j = 0; j < 4; ++j) {
        const int row = m0 + wm + mt * 16 + l4 * 4 + j;
        Out[(size_t)row * DIM + col] = acc[mt][nt][j] + bb;
      }
  }
}

// -------- flash attention (r7 best-measured form): LDS-staged, 32x32 MFMA --------
// Grid (S/128, H, N) = 512 blocks; 4 waves; wave owns 32 q rows. Double-buffered
// 16KB K/V tiles via async global_load_lds; one __syncthreads per iter. Max-free
// softmax (scores bounded << f16 range): P = exp2(s), l normalizes.
__global__ __launch_bounds__(256, 2) void attn_kernel(
    const f16* __restrict__ Q, const f16* __restrict__ K,
    const f16* __restrict__ Vt, f16* __restrict__ AO) {
  const int qt = blockIdx.x, h = blockIdx.y, b = blockIdx.z;
  const int tid = threadIdx.x;
  const int lane = tid & 63, wid = tid >> 6;
  const int l31 = lane & 31, hi = lane >> 5;

  __shared__ __align__(16) char kv_lds[2][16384];  // [buf][K 8KB | V 8KB]

  const int q0 = qt * 128 + wid * 32;
  const size_t panel = (size_t)(b * NHEAD + h) * (S_LEN * HDIM);
  const f16* Qp = Q + panel + (size_t)(q0 >> 5) * 2048;
  const char* KpB = (const char*)(K + panel);
  const char* VpB = (const char*)(Vt + panel);

  f16x8 qf[4];
#pragma unroll
  for (int sk = 0; sk < 4; ++sk)
    qf[sk] = *(const f16x8*)(Qp + sk * 512 + hi * 256 + l31 * 8);

  f32x16 accO[2] = {};            // O^T[d][q]: dt in {0,1}, col=q=l31
  float lacc0 = 0.f, lacc1 = 0.f, lacc2 = 0.f, lacc3 = 0.f;

  auto STAGE = [&](int it, int buf) {
    const char* gK = KpB + (size_t)it * 8192 + tid * 16;
    const char* gV = VpB + (size_t)it * 8192 + tid * 16;
    char* lb = &kv_lds[buf][wid * 1024];
    gload16(gK,        lb);
    gload16(gK + 4096, lb + 4096);
    gload16(gV,        lb + 8192);
    gload16(gV + 4096, lb + 12288);
  };

  auto QK = [&](int buf, f32x16 (&st)[2]) {
    const char* lk = &kv_lds[buf][0];
    f16x8 kf[2][4];
#pragma unroll
    for (int tt = 0; tt < 2; ++tt)
#pragma unroll
      for (int sk = 0; sk < 4; ++sk)
        kf[tt][sk] = *(const f16x8*)(lk + tt * 4096 + sk * 1024 + lane * 16);
    __builtin_amdgcn_s_setprio(1);
#pragma unroll
    for (int tt = 0; tt < 2; ++tt) {
      st[tt] = (f32x16)(0.f);
#pragma unroll
      for (int sk = 0; sk < 4; ++sk)
        st[tt] = __builtin_amdgcn_mfma_f32_32x32x16_f16(kf[tt][sk], qf[sk], st[tt], 0, 0, 0);
    }
    __builtin_amdgcn_s_setprio(0);
  };

  auto PHASE = [&](f32x16 (&st)[2], int buf) {
    const char* lv = &kv_lds[buf][8192];
    f16x8 vf[2][4];
#pragma unroll
    for (int dt = 0; dt < 2; ++dt)
#pragma unroll
      for (int s = 0; s < 4; ++s)
        vf[dt][s] = *(const f16x8*)(lv + dt * 4096 + s * 1024 + lane * 16);

    u32 pk[2][8];
#pragma unroll
    for (int tt = 0; tt < 2; ++tt)
#pragma unroll
      for (int j = 0; j < 8; ++j) {
        const float p0 = fast_exp2(st[tt][2 * j]);
        const float p1 = fast_exp2(st[tt][2 * j + 1]);
        const float ps = p0 + p1;
        if (((tt * 8 + j) & 3) == 0) lacc0 += ps;
        else if (((tt * 8 + j) & 3) == 1) lacc1 += ps;
        else if (((tt * 8 + j) & 3) == 2) lacc2 += ps;
        else lacc3 += ps;
        union { hf16x2 h; u32 w; } cv;
        cv.h = __builtin_amdgcn_cvt_pkrtz(p0, p1);
        pk[tt][j] = cv.w;
      }

    __builtin_amdgcn_s_setprio(1);
#pragma unroll
    for (int s = 0; s < 4; ++s) {
      const int tt = s >> 1, sl = s & 1;
      u32 w0 = pk[tt][4 * sl + 0], w2 = pk[tt][4 * sl + 2];
      u32 w1 = pk[tt][4 * sl + 1], w3 = pk[tt][4 * sl + 3];
      asm("v_permlane32_swap_b32 %0, %1" : "+v"(w0), "+v"(w2));
      asm("v_permlane32_swap_b32 %0, %1" : "+v"(w1), "+v"(w3));
      union { u32 w[4]; f16x8 v; } pf;
      pf.w[0] = w0; pf.w[1] = w1; pf.w[2] = w2; pf.w[3] = w3;
      accO[0] = __builtin_amdgcn_mfma_f32_32x32x16_f16(vf[0][s], pf.v, accO[0], 0, 0, 0);
      accO[1] = __builtin_amdgcn_mfma_f32_32x32x16_f16(vf[1][s], pf.v, accO[1], 0, 0, 0);
    }
    __builtin_amdgcn_s_setprio(0);
  };

  const int NIT = S_LEN / 64;  // 32
  STAGE(0, 0);
  __syncthreads();

  f32x16 st[2];
  for (int it = 0; it < NIT; ++it) {
    const int buf = it & 1;
    if (it + 1 < NIT) STAGE(it + 1, buf ^ 1);
    QK(buf, st);
    PHASE(st, buf);
    __syncthreads();
  }

  const float l_loc = (lacc0 + lacc1) + (lacc2 + lacc3);
  const float l_all = l_loc + __shfl_xor(l_loc, 32);
  const float inv = 1.f / l_all;
  f16* aop = AO + ((size_t)(b * S_LEN + q0 + l31)) * DIM + h * HDIM;
#pragma unroll
  for (int dt = 0; dt < 2; ++dt)
#pragma unroll
    for (int j = 0; j < 8; ++j) {
      union { f16x2 h; u32 w; } cv;
      cv.h[0] = (f16)(accO[dt][2 * j] * inv);
      cv.h[1] = (f16)(accO[dt][2 * j + 1] * inv);
      const int d = ((2 * j) & 3) + 8 * ((2 * j) >> 2) + 4 * hi + dt * 32;
      *(f16x2*)(aop + d) = cv.h;
    }
}

extern "C" void kernel_launch(void* const* d_in, const int* in_sizes, int n_in,
                              void* d_out, int out_size, void* d_ws, size_t ws_size,
                              hipStream_t stream) {
  (void)in_sizes; (void)n_in; (void)out_size; (void)ws_size;
  const float* q  = (const float*)d_in[0];
  const float* k  = (const float*)d_in[1];
  const float* v  = (const float*)d_in[2];
  const float* Wq = (const float*)d_in[3];
  const float* bq = (const float*)d_in[4];
  const float* Wk = (const float*)d_in[5];
  const float* bk = (const float*)d_in[6];
  const float* Wv = (const float*)d_in[7];
  const float* bv = (const float*)d_in[8];
  const float* Wp = (const float*)d_in[9];
  const float* bp = (const float*)d_in[10];

  char* ws = (char*)d_ws;
  f16* Xq  = (f16*)(ws + OFF_XQ);
  f16* Xk  = (f16*)(ws + OFF_XK);
  f16* Xv  = (f16*)(ws + OFF_XV);
  f16* Wt  = (f16*)(ws + OFF_WT);
  f16* Qs  = (f16*)(ws + OFF_Q);
  f16* Kh  = (f16*)(ws + OFF_K);
  f16* Vts = (f16*)(ws + OFF_VT);
  f16* AO  = (f16*)(ws + OFF_AO);

  cast_x_kernel<<<dim3(2048, 3, 1), 256, 0, stream>>>(q, k, v, Xq, Xk, Xv);
  transpose_w_kernel<<<dim3(16, 16, 4), 256, 0, stream>>>(Wq, Wk, Wv, Wp, Wt);
  proj_kernel<<<dim3(32, 8, 3), 256, 0, stream>>>(Xq, Xk, Xv, Wt, bq, bk, bv, Qs, Kh, Vts);
  attn_kernel<<<dim3(16, 16, 2), 256, 0, stream>>>(Qs, Kh, Vts, AO);
  outproj_kernel<<<dim3(64, 8, 1), 256, 0, stream>>>(AO, Wt + 3ull * DIM * DIM, bp, (float*)d_out);
}

// Round 16
// 128.480 us; speedup vs baseline: 1.0958x; 1.0025x over previous
//
#include <hip/hip_runtime.h>
#include <cstdint>
#include <cstddef>

typedef _Float16 f16;
typedef f16 f16x2 __attribute__((ext_vector_type(2)));
typedef f16 f16x8 __attribute__((ext_vector_type(8)));
typedef __fp16 hf16x2 __attribute__((ext_vector_type(2)));  // cvt_pkrtz return type
typedef float f32x4 __attribute__((ext_vector_type(4)));
typedef float f32x16 __attribute__((ext_vector_type(16)));
typedef unsigned int u32;

#define S_LEN 2048
#define DIM 1024
#define NBATCH 2
#define NHEAD 16
#define HDIM 64
#define M_TOT (NBATCH * S_LEN)  // 4096

// Q scale folds 1/sqrt(Hd) AND log2(e) so softmax uses exp2 directly.
#define QSCALE 0.18033688011112042f  // 0.125 * 1.4426950408889634

// ---- workspace layout (bytes) ----
#define OFF_XQ 0ull
#define OFF_XK (OFF_XQ + (size_t)M_TOT * DIM * 2)
#define OFF_XV (OFF_XK + (size_t)M_TOT * DIM * 2)
#define OFF_WT (OFF_XV + (size_t)M_TOT * DIM * 2)          // 4 mats, [N][K] f16
#define OFF_Q  (OFF_WT + 4ull * DIM * DIM * 2)             // fragment-native layouts
#define OFF_K  (OFF_Q + (size_t)M_TOT * DIM * 2)
#define OFF_VT (OFF_K + (size_t)M_TOT * DIM * 2)
#define OFF_AO (OFF_VT + (size_t)M_TOT * DIM * 2)

// ---------------- async global->LDS (width 16) ----------------
typedef const __attribute__((address_space(1))) void GVp;
typedef __attribute__((address_space(3))) void LVp;
__device__ __forceinline__ void gload16(const void* g, void* l) {
  __builtin_amdgcn_global_load_lds((GVp*)g, (LVp*)l, 16, 0, 0);
}

__device__ __forceinline__ float fast_exp2(float x) {
  float r;
  asm("v_exp_f32 %0, %1" : "=v"(r) : "v"(x));
  return r;
}

// publish LDS writes; NO vmcnt drain (reg loads are wave-private and fly across)
#define SYNCL()                                              \
  do {                                                       \
    asm volatile("s_waitcnt lgkmcnt(0)" ::: "memory");       \
    __builtin_amdgcn_sched_barrier(0);                       \
    __builtin_amdgcn_s_barrier();                            \
    __builtin_amdgcn_sched_barrier(0);                       \
  } while (0)

// ---------------- cast fp32 -> fp16, 8 elems/thread ----------------
__global__ __launch_bounds__(256) void cast_x_kernel(
    const float* __restrict__ q, const float* __restrict__ k, const float* __restrict__ v,
    f16* __restrict__ oq, f16* __restrict__ ok, f16* __restrict__ ov) {
  const float* src = blockIdx.y == 0 ? q : blockIdx.y == 1 ? k : v;
  f16* dst = blockIdx.y == 0 ? oq : blockIdx.y == 1 ? ok : ov;
  size_t i = ((size_t)blockIdx.x * 256 + threadIdx.x) * 8;
  float4 a = *(const float4*)(src + i);
  float4 b = *(const float4*)(src + i + 4);
  f16x8 o;
  o[0] = (f16)a.x; o[1] = (f16)a.y; o[2] = (f16)a.z; o[3] = (f16)a.w;
  o[4] = (f16)b.x; o[5] = (f16)b.y; o[6] = (f16)b.z; o[7] = (f16)b.w;
  *(f16x8*)(dst + i) = o;
}

// ---------------- W [K][N] fp32 -> Wt [N][K] fp16 ----------------
__global__ __launch_bounds__(256) void transpose_w_kernel(
    const float* __restrict__ Wq, const float* __restrict__ Wk,
    const float* __restrict__ Wv, const float* __restrict__ Wp,
    f16* __restrict__ out) {
  const float* W = blockIdx.z == 0 ? Wq : blockIdx.z == 1 ? Wk : blockIdx.z == 2 ? Wv : Wp;
  f16* Wt = out + (size_t)blockIdx.z * DIM * DIM;
  __shared__ f16 tile[64][72];
  const int kt = blockIdx.x * 64, nt = blockIdx.y * 64;
  const int t = threadIdx.x, r = t >> 2, c0 = (t & 3) * 16;
#pragma unroll
  for (int i = 0; i < 16; i += 4) {
    float4 vv = *(const float4*)(W + (size_t)(kt + r) * DIM + nt + c0 + i);
    tile[r][c0 + i + 0] = (f16)vv.x; tile[r][c0 + i + 1] = (f16)vv.y;
    tile[r][c0 + i + 2] = (f16)vv.z; tile[r][c0 + i + 3] = (f16)vv.w;
  }
  __syncthreads();
  f16x8 o0, o1;
#pragma unroll
  for (int i = 0; i < 8; ++i) { o0[i] = tile[c0 + i][r]; o1[i] = tile[c0 + 8 + i][r]; }
  *(f16x8*)(Wt + (size_t)(nt + r) * DIM + kt + c0) = o0;
  *(f16x8*)(Wt + (size_t)(nt + r) * DIM + kt + c0 + 8) = o1;
}

// ------- 128x128 f16 GEMM core, T2-swizzled LDS (r13-validated) -------
__device__ __forceinline__ void gemm_core_sw(const f16* __restrict__ A, const f16* __restrict__ B,
                                             char* lds, f32x4 acc[4][4]) {
  const int tid = threadIdx.x;
  const int wid = tid >> 6, lane = tid & 63;
  const int l15 = lane & 15, l4 = lane >> 4;
  const int wm = (wid >> 1) * 64, wn = (wid & 1) * 64;
  const int rr = tid >> 2, cc = tid & 3;
  const int ccs = cc ^ ((rr >> 1) & 3);                    // pre-swizzled source slot
  const f16* gA = A + (size_t)rr * DIM + ccs * 8;
  const f16* gB = B + (size_t)rr * DIM + ccs * 8;
  const int ldst = wid * 1024;

  gload16(gA,            lds + ldst);
  gload16(gA + 64 * DIM, lds + 4096 + ldst);
  gload16(gB,            lds + 8192 + ldst);
  gload16(gB + 64 * DIM, lds + 12288 + ldst);
  __syncthreads();

  const int sw = (l15 >> 1) & 3;
  for (int kt = 0; kt < DIM / 32; ++kt) {
    char* cur = lds + (kt & 1) * 16384;
    if (kt + 1 < DIM / 32) {
      char* nxt = lds + ((kt + 1) & 1) * 16384;
      const f16* ga = gA + (kt + 1) * 32;
      const f16* gb = gB + (kt + 1) * 32;
      gload16(ga,            nxt + ldst);
      gload16(ga + 64 * DIM, nxt + 4096 + ldst);
      gload16(gb,            nxt + 8192 + ldst);
      gload16(gb + 64 * DIM, nxt + 12288 + ldst);
    }
    f16x8 af[4], bf[4];
#pragma unroll
    for (int mt = 0; mt < 4; ++mt)
      af[mt] = *(const f16x8*)(cur + (wm + mt * 16 + l15) * 64 + (l4 ^ sw) * 16);
#pragma unroll
    for (int nt = 0; nt < 4; ++nt)
      bf[nt] = *(const f16x8*)(cur + 8192 + (wn + nt * 16 + l15) * 64 + (l4 ^ sw) * 16);
#pragma unroll
    for (int mt = 0; mt < 4; ++mt)
#pragma unroll
      for (int nt = 0; nt < 4; ++nt)
        acc[mt][nt] = __builtin_amdgcn_mfma_f32_16x16x32_f16(af[mt], bf[nt], acc[mt][nt], 0, 0, 0);
    __syncthreads();
  }
}

// Fragment-native addresses (elements) within one (batch,head) panel:
//  Q/K: tile32 = s>>5 ; addr = tile32*2048 + (d>>4)*512 + ((d>>3)&1)*256 + (s&31)*8 + (d&7)
//  V:   tile64 = s>>6 ; addr = tile64*4096 + (d>>5)*2048 + ((s>>4)&3)*512 + ((s>>3)&1)*256 + (d&31)*8 + (s&7)

// ---------------- batched QKV projection (f16 inputs) ----------------
__global__ __launch_bounds__(256) void proj_kernel(
    const f16* __restrict__ Xq, const f16* __restrict__ Xk, const f16* __restrict__ Xv,
    const f16* __restrict__ Wt,
    const float* __restrict__ bq, const float* __restrict__ bk, const float* __restrict__ bv,
    f16* __restrict__ Q, f16* __restrict__ Kh, f16* __restrict__ Vt) {
  __shared__ __align__(16) char lds[32768];
  const int m0 = blockIdx.x * 128, n0 = blockIdx.y * 128;
  const int z = blockIdx.z;
  const f16* X = z == 0 ? Xq : z == 1 ? Xk : Xv;
  const f16* W = Wt + (size_t)z * DIM * DIM;
  const float* bias = z == 0 ? bq : z == 1 ? bk : bv;
  f32x4 acc[4][4] = {};
  gemm_core_sw(X + (size_t)m0 * DIM, W + (size_t)n0 * DIM, lds, acc);

  const int tid = threadIdx.x, wid = tid >> 6, lane = tid & 63;
  const int l15 = lane & 15, l4 = lane >> 4;
  const int wm = (wid >> 1) * 64, wn = (wid & 1) * 64;
#pragma unroll
  for (int nt = 0; nt < 4; ++nt) {
    const int col = n0 + wn + nt * 16 + l15;
    const float bb = bias[col];
    const int hh = col >> 6, d = col & 63;
#pragma unroll
    for (int mt = 0; mt < 4; ++mt)
#pragma unroll
      for (int j = 0; j < 4; ++j) {
        const int row = m0 + wm + mt * 16 + l4 * 4 + j;
        const float v = acc[mt][nt][j] + bb;
        const int n = row >> 11, s = row & (S_LEN - 1);
        const size_t panel = (size_t)(n * NHEAD + hh);
        if (z == 0) {
          const size_t a = panel * (S_LEN * HDIM) + (size_t)(s >> 5) * 2048 +
                           (d >> 4) * 512 + ((d >> 3) & 1) * 256 + (s & 31) * 8 + (d & 7);
          Q[a] = (f16)(v * QSCALE);
        } else if (z == 1) {
          const size_t a = panel * (S_LEN * HDIM) + (size_t)(s >> 5) * 2048 +
                           (d >> 4) * 512 + ((d >> 3) & 1) * 256 + (s & 31) * 8 + (d & 7);
          Kh[a] = (f16)v;
        } else {
          const size_t a = panel * (S_LEN * HDIM) + (size_t)(s >> 6) * 4096 +
                           (d >> 5) * 2048 + ((s >> 4) & 3) * 512 + ((s >> 3) & 1) * 256 +
                           (d & 31) * 8 + (s & 7);
          Vt[a] = (f16)v;
        }
      }
  }
}

// ------- 64x128 f16 GEMM core (outproj): 512 blocks -> 2 blocks/CU -------
__device__ __forceinline__ void gemm_core_sw64(const f16* __restrict__ A, const f16* __restrict__ B,
                                               char* lds, f32x4 acc[2][4]) {
  const int tid = threadIdx.x;
  const int wid = tid >> 6, lane = tid & 63;
  const int l15 = lane & 15, l4 = lane >> 4;
  const int wm = (wid >> 1) * 32, wn = (wid & 1) * 64;
  const int rr = tid >> 2, cc = tid & 3;
  const int ccs = cc ^ ((rr >> 1) & 3);                    // pre-swizzled source slot
  const f16* gA = A + (size_t)rr * DIM + ccs * 8;          // rows 0..63
  const f16* gB = B + (size_t)rr * DIM + ccs * 8;
  const int ldst = wid * 1024;

  gload16(gA,            lds + ldst);                      // A rows 0..63
  gload16(gB,            lds + 4096 + ldst);               // B rows 0..63
  gload16(gB + 64 * DIM, lds + 8192 + ldst);               // B rows 64..127
  __syncthreads();

  const int sw = (l15 >> 1) & 3;
  for (int kt = 0; kt < DIM / 32; ++kt) {
    char* cur = lds + (kt & 1) * 12288;
    if (kt + 1 < DIM / 32) {
      char* nxt = lds + ((kt + 1) & 1) * 12288;
      const f16* ga = gA + (kt + 1) * 32;
      const f16* gb = gB + (kt + 1) * 32;
      gload16(ga,            nxt + ldst);
      gload16(gb,            nxt + 4096 + ldst);
      gload16(gb + 64 * DIM, nxt + 8192 + ldst);
    }
    f16x8 af[2], bf[4];
#pragma unroll
    for (int mt = 0; mt < 2; ++mt)
      af[mt] = *(const f16x8*)(cur + (wm + mt * 16 + l15) * 64 + (l4 ^ sw) * 16);
#pragma unroll
    for (int nt = 0; nt < 4; ++nt)
      bf[nt] = *(const f16x8*)(cur + 4096 + (wn + nt * 16 + l15) * 64 + (l4 ^ sw) * 16);
#pragma unroll
    for (int mt = 0; mt < 2; ++mt)
#pragma unroll
      for (int nt = 0; nt < 4; ++nt)
        acc[mt][nt] = __builtin_amdgcn_mfma_f32_16x16x32_f16(af[mt], bf[nt], acc[mt][nt], 0, 0, 0);
    __syncthreads();
  }
}

// ---------------- output projection -> fp32 d_out (64-row tile, 2 blocks/CU) --------
__global__ __launch_bounds__(256) void outproj_kernel(
    const f16* __restrict__ A, const f16* __restrict__ Wt,
    const float* __restrict__ bias, float* __restrict__ Out) {
  __shared__ __align__(16) char lds[24576];
  const int m0 = blockIdx.x * 64, n0 = blockIdx.y * 128;
  f32x4 acc[2][4] = {};
  gemm_core_sw64(A + (size_t)m0 * DIM, Wt + (size_t)n0 * DIM, lds, acc);

  const int tid = threadIdx.x, wid = tid >> 6, lane = tid & 63;
  const int l15 = lane & 15, l4 = lane >> 4;
  const int wm = (wid >> 1) * 32, wn = (wid & 1) * 64;
#pragma unroll
  for (int nt = 0; nt < 4; ++nt) {
    const int col = n0 + wn + nt * 16 + l15;
    const float bb = bias[col];
#pragma unroll
    for (int mt = 0; mt < 2; ++mt)
#pragma unroll
      for (int j = 0; j < 4; ++j) {
        const int row = m0 + wm + mt * 16 + l4 * 4 + j;
        Out[(size_t)row * DIM + col] = acc[mt][nt][j] + bb;
      }
  }
}

// -------- flash attention: reg-staged async-split (T14) + XCD swizzle (T1) --------
// 512 blocks linear, 4 waves. Staging: global->reg issued at iter TOP (wave-private,
// flies across barriers), ds_write after compute (compiler inserts the vmcnt wait for
// exactly those regs), then lgkmcnt(0)+s_barrier — NO vmcnt(0) drain anywhere in-loop.
// T1: contiguous 64-block chunks per XCD => each (h,b) K/V panel lives on ONE XCD's L2.
__global__ __launch_bounds__(256, 2) void attn_kernel(
    const f16* __restrict__ Q, const f16* __restrict__ K,
    const f16* __restrict__ Vt, f16* __restrict__ AO) {
  const int bid = blockIdx.x;
  const int sbid = (bid & 7) * 64 + (bid >> 3);    // bijective: 512 % 8 == 0
  const int qt = sbid & 15, h = (sbid >> 4) & 15, b = sbid >> 8;
  const int tid = threadIdx.x;
  const int lane = tid & 63, wid = tid >> 6;
  const int l31 = lane & 31, hi = lane >> 5;

  __shared__ __align__(16) char kv_lds[2][16384];  // [buf][K 8KB | V 8KB]

  const int q0 = qt * 128 + wid * 32;
  const size_t panel = (size_t)(b * NHEAD + h) * (S_LEN * HDIM);
  const f16* Qp = Q + panel + (size_t)(q0 >> 5) * 2048;
  const char* KpB = (const char*)(K + panel);
  const char* VpB = (const char*)(Vt + panel);

  f16x8 qf[4];
#pragma unroll
  for (int sk = 0; sk < 4; ++sk)
    qf[sk] = *(const f16x8*)(Qp + sk * 512 + hi * 256 + l31 * 8);

  f32x16 accO[2] = {};            // O^T[d][q]: dt in {0,1}, col=q=l31
  float lacc0 = 0.f, lacc1 = 0.f, lacc2 = 0.f, lacc3 = 0.f;

  // ---- reg staging: load tile -> 4x f32x4, write to LDS later ----
  auto LOADR = [&](int it, f32x4 (&R)[4]) {
    const char* gK = KpB + (size_t)it * 8192 + tid * 16;
    const char* gV = VpB + (size_t)it * 8192 + tid * 16;
    R[0] = *(const f32x4*)(gK);
    R[1] = *(const f32x4*)(gK + 4096);
    R[2] = *(const f32x4*)(gV);
    R[3] = *(const f32x4*)(gV + 4096);
  };
  auto WRITER = [&](const f32x4 (&R)[4], int buf) {
    char* lb = &kv_lds[buf][tid * 16 + (tid >> 6) * 0];   // same linear layout as before
    // layout identical to old gload_lds: [wid*1024 + lane*16] within each 4KB chunk
    char* p = &kv_lds[buf][(tid >> 6) * 1024 + (tid & 63) * 16];
    (void)lb;
    *(f32x4*)(p)         = R[0];
    *(f32x4*)(p + 4096)  = R[1];
    *(f32x4*)(p + 8192)  = R[2];
    *(f32x4*)(p + 12288) = R[3];
  };

  auto QK = [&](int buf, f32x16 (&st)[2]) {
    const char* lk = &kv_lds[buf][0];
    f16x8 kf[2][4];
#pragma unroll
    for (int tt = 0; tt < 2; ++tt)
#pragma unroll
      for (int sk = 0; sk < 4; ++sk)
        kf[tt][sk] = *(const f16x8*)(lk + tt * 4096 + sk * 1024 + lane * 16);
    __builtin_amdgcn_s_setprio(1);
#pragma unroll
    for (int tt = 0; tt < 2; ++tt) {
      st[tt] = (f32x16)(0.f);
#pragma unroll
      for (int sk = 0; sk < 4; ++sk)
        st[tt] = __builtin_amdgcn_mfma_f32_32x32x16_f16(kf[tt][sk], qf[sk], st[tt], 0, 0, 0);
    }
    __builtin_amdgcn_s_setprio(0);
  };

  auto PHASE = [&](f32x16 (&st)[2], int buf) {
    const char* lv = &kv_lds[buf][8192];
    f16x8 vf[2][4];
#pragma unroll
    for (int dt = 0; dt < 2; ++dt)
#pragma unroll
      for (int s = 0; s < 4; ++s)
        vf[dt][s] = *(const f16x8*)(lv + dt * 4096 + s * 1024 + lane * 16);

    u32 pk[2][8];
#pragma unroll
    for (int tt = 0; tt < 2; ++tt)
#pragma unroll
      for (int j = 0; j < 8; ++j) {
        const float p0 = fast_exp2(st[tt][2 * j]);
        const float p1 = fast_exp2(st[tt][2 * j + 1]);
        const float ps = p0 + p1;
        if (((tt * 8 + j) & 3) == 0) lacc0 += ps;
        else if (((tt * 8 + j) & 3) == 1) lacc1 += ps;
        else if (((tt * 8 + j) & 3) == 2) lacc2 += ps;
        else lacc3 += ps;
        union { hf16x2 h; u32 w; } cv;
        cv.h = __builtin_amdgcn_cvt_pkrtz(p0, p1);
        pk[tt][j] = cv.w;
      }

    __builtin_amdgcn_s_setprio(1);
#pragma unroll
    for (int s = 0; s < 4; ++s) {
      const int tt = s >> 1, sl = s & 1;
      u32 w0 = pk[tt][4 * sl + 0], w2 = pk[tt][4 * sl + 2];
      u32 w1 = pk[tt][4 * sl + 1], w3 = pk[tt][4 * sl + 3];
      asm("v_permlane32_swap_b32 %0, %1" : "+v"(w0), "+v"(w2));
      asm("v_permlane32_swap_b32 %0, %1" : "+v"(w1), "+v"(w3));
      union { u32 w[4]; f16x8 v; } pf;
      pf.w[0] = w0; pf.w[1] = w1; pf.w[2] = w2; pf.w[3] = w3;
      accO[0] = __builtin_amdgcn_mfma_f32_32x32x16_f16(vf[0][s], pf.v, accO[0], 0, 0, 0);
      accO[1] = __builtin_amdgcn_mfma_f32_32x32x16_f16(vf[1][s], pf.v, accO[1], 0, 0, 0);
    }
    __builtin_amdgcn_s_setprio(0);
  };

  const int NIT = S_LEN / 64;  // 32 (even)

  f32x4 RA[4], RB[4];
  f32x16 st[2];
  LOADR(0, RA);
  WRITER(RA, 0);               // compiler waits RA's vmcnt here (prologue only)
  LOADR(1, RB);                // in flight across the first barrier
  SYNCL();

  for (int it = 0; it < NIT; it += 2) {
    // even sub-iter: compute L0 = tile it; publish tile it+1; prefetch it+2
    if (it + 2 < NIT) LOADR(it + 2, RA);
    QK(0, st);
    PHASE(st, 0);
    WRITER(RB, 1);             // vmcnt wait auto-inserted for RB only
    SYNCL();
    // odd sub-iter: compute L1 = tile it+1; publish tile it+2; prefetch it+3
    if (it + 3 < NIT) LOADR(it + 3, RB);
    QK(1, st);
    PHASE(st, 1);
    if (it + 2 < NIT) WRITER(RA, 0);
    SYNCL();
  }

  const float l_loc = (lacc0 + lacc1) + (lacc2 + lacc3);
  const float l_all = l_loc + __shfl_xor(l_loc, 32);
  const float inv = 1.f / l_all;
  f16* aop = AO + ((size_t)(b * S_LEN + q0 + l31)) * DIM + h * HDIM;
#pragma unroll
  for (int dt = 0; dt < 2; ++dt)
#pragma unroll
    for (int j = 0; j < 8; ++j) {
      union { f16x2 h; u32 w; } cv;
      cv.h[0] = (f16)(accO[dt][2 * j] * inv);
      cv.h[1] = (f16)(accO[dt][2 * j + 1] * inv);
      const int d = ((2 * j) & 3) + 8 * ((2 * j) >> 2) + 4 * hi + dt * 32;
      *(f16x2*)(aop + d) = cv.h;
    }
}

extern "C" void kernel_launch(void* const* d_in, const int* in_sizes, int n_in,
                              void* d_out, int out_size, void* d_ws, size_t ws_size,
                              hipStream_t stream) {
  (void)in_sizes; (void)n_in; (void)out_size; (void)ws_size;
  const float* q  = (const float*)d_in[0];
  const float* k  = (const float*)d_in[1];
  const float* v  = (const float*)d_in[2];
  const float* Wq = (const float*)d_in[3];
  const float* bq = (const float*)d_in[4];
  const float* Wk = (const float*)d_in[5];
  const float* bk = (const float*)d_in[6];
  const float* Wv = (const float*)d_in[7];
  const float* bv = (const float*)d_in[8];
  const float* Wp = (const float*)d_in[9];
  const float* bp = (const float*)d_in[10];

  char* ws = (char*)d_ws;
  f16* Xq  = (f16*)(ws + OFF_XQ);
  f16* Xk  = (f16*)(ws + OFF_XK);
  f16* Xv  = (f16*)(ws + OFF_XV);
  f16* Wt  = (f16*)(ws + OFF_WT);
  f16* Qs  = (f16*)(ws + OFF_Q);
  f16* Kh  = (f16*)(ws + OFF_K);
  f16* Vts = (f16*)(ws + OFF_VT);
  f16* AO  = (f16*)(ws + OFF_AO);

  cast_x_kernel<<<dim3(2048, 3, 1), 256, 0, stream>>>(q, k, v, Xq, Xk, Xv);
  transpose_w_kernel<<<dim3(16, 16, 4), 256, 0, stream>>>(Wq, Wk, Wv, Wp, Wt);
  proj_kernel<<<dim3(32, 8, 3), 256, 0, stream>>>(Xq, Xk, Xv, Wt, bq, bk, bv, Qs, Kh, Vts);
  attn_kernel<<<dim3(512, 1, 1), 256, 0, stream>>>(Qs, Kh, Vts, AO);
  outproj_kernel<<<dim3(64, 8, 1), 256, 0, stream>>>(AO, Wt + 3ull * DIM * DIM, bp, (float*)d_out);
}

// Round 17
// 126.291 us; speedup vs baseline: 1.1148x; 1.0173x over previous
//
#include <hip/hip_runtime.h>
#include <cstdint>
#include <cstddef>

typedef _Float16 f16;
typedef f16 f16x2 __attribute__((ext_vector_type(2)));
typedef f16 f16x8 __attribute__((ext_vector_type(8)));
typedef __fp16 hf16x2 __attribute__((ext_vector_type(2)));  // cvt_pkrtz return type
typedef float f32x4 __attribute__((ext_vector_type(4)));
typedef float f32x16 __attribute__((ext_vector_type(16)));
typedef unsigned int u32;

#define S_LEN 2048
#define DIM 1024
#define NBATCH 2
#define NHEAD 16
#define HDIM 64
#define M_TOT (NBATCH * S_LEN)  // 4096

// Q scale folds 1/sqrt(Hd) AND log2(e) so softmax uses exp2 directly.
#define QSCALE 0.18033688011112042f  // 0.125 * 1.4426950408889634

// ---- workspace layout (bytes) ----
#define OFF_XQ 0ull
#define OFF_XK (OFF_XQ + (size_t)M_TOT * DIM * 2)
#define OFF_XV (OFF_XK + (size_t)M_TOT * DIM * 2)
#define OFF_WT (OFF_XV + (size_t)M_TOT * DIM * 2)          // 4 mats, [N][K] f16
#define OFF_Q  (OFF_WT + 4ull * DIM * DIM * 2)             // fragment-native layouts
#define OFF_K  (OFF_Q + (size_t)M_TOT * DIM * 2)
#define OFF_VT (OFF_K + (size_t)M_TOT * DIM * 2)
#define OFF_AO (OFF_VT + (size_t)M_TOT * DIM * 2)

// ---------------- async global->LDS (width 16) ----------------
typedef const __attribute__((address_space(1))) void GVp;
typedef __attribute__((address_space(3))) void LVp;
__device__ __forceinline__ void gload16(const void* g, void* l) {
  __builtin_amdgcn_global_load_lds((GVp*)g, (LVp*)l, 16, 0, 0);
}

__device__ __forceinline__ float fast_exp2(float x) {
  float r;
  asm("v_exp_f32 %0, %1" : "=v"(r) : "v"(x));
  return r;
}

// publish LDS writes; NO vmcnt drain (reg loads are wave-private and fly across)
#define SYNCL()                                              \
  do {                                                       \
    asm volatile("s_waitcnt lgkmcnt(0)" ::: "memory");       \
    __builtin_amdgcn_sched_barrier(0);                       \
    __builtin_amdgcn_s_barrier();                            \
    __builtin_amdgcn_sched_barrier(0);                       \
  } while (0)

// ------- merged prep: cast X (y=0..2) + transpose W (y=3, x<1024) -------
__global__ __launch_bounds__(256) void prep_kernel(
    const float* __restrict__ q, const float* __restrict__ k, const float* __restrict__ v,
    const float* __restrict__ Wq, const float* __restrict__ Wk,
    const float* __restrict__ Wv, const float* __restrict__ Wp,
    f16* __restrict__ oq, f16* __restrict__ ok, f16* __restrict__ ov,
    f16* __restrict__ wt_out) {
  __shared__ f16 tile[64][72];
  if (blockIdx.y < 3) {
    const float* src = blockIdx.y == 0 ? q : blockIdx.y == 1 ? k : v;
    f16* dst = blockIdx.y == 0 ? oq : blockIdx.y == 1 ? ok : ov;
    size_t i = ((size_t)blockIdx.x * 256 + threadIdx.x) * 8;
    float4 a = *(const float4*)(src + i);
    float4 b = *(const float4*)(src + i + 4);
    f16x8 o;
    o[0] = (f16)a.x; o[1] = (f16)a.y; o[2] = (f16)a.z; o[3] = (f16)a.w;
    o[4] = (f16)b.x; o[5] = (f16)b.y; o[6] = (f16)b.z; o[7] = (f16)b.w;
    *(f16x8*)(dst + i) = o;
    return;
  }
  if (blockIdx.x >= 1024) return;                  // uniform per block: safe
  const int bz = blockIdx.x >> 8;                  // 0..3 -> Wq/Wk/Wv/Wp
  const int bx = blockIdx.x & 15, by = (blockIdx.x >> 4) & 15;
  const float* W = bz == 0 ? Wq : bz == 1 ? Wk : bz == 2 ? Wv : Wp;
  f16* Wt = wt_out + (size_t)bz * DIM * DIM;
  const int kt = bx * 64, nt = by * 64;
  const int t = threadIdx.x, r = t >> 2, c0 = (t & 3) * 16;
#pragma unroll
  for (int i = 0; i < 16; i += 4) {
    float4 vv = *(const float4*)(W + (size_t)(kt + r) * DIM + nt + c0 + i);
    tile[r][c0 + i + 0] = (f16)vv.x; tile[r][c0 + i + 1] = (f16)vv.y;
    tile[r][c0 + i + 2] = (f16)vv.z; tile[r][c0 + i + 3] = (f16)vv.w;
  }
  __syncthreads();
  f16x8 o0, o1;
#pragma unroll
  for (int i = 0; i < 8; ++i) { o0[i] = tile[c0 + i][r]; o1[i] = tile[c0 + 8 + i][r]; }
  *(f16x8*)(Wt + (size_t)(nt + r) * DIM + kt + c0) = o0;
  *(f16x8*)(Wt + (size_t)(nt + r) * DIM + kt + c0 + 8) = o1;
}

// ------- 128x128 f16 GEMM core, T2-swizzled LDS (r13-validated) -------
__device__ __forceinline__ void gemm_core_sw(const f16* __restrict__ A, const f16* __restrict__ B,
                                             char* lds, f32x4 acc[4][4]) {
  const int tid = threadIdx.x;
  const int wid = tid >> 6, lane = tid & 63;
  const int l15 = lane & 15, l4 = lane >> 4;
  const int wm = (wid >> 1) * 64, wn = (wid & 1) * 64;
  const int rr = tid >> 2, cc = tid & 3;
  const int ccs = cc ^ ((rr >> 1) & 3);                    // pre-swizzled source slot
  const f16* gA = A + (size_t)rr * DIM + ccs * 8;
  const f16* gB = B + (size_t)rr * DIM + ccs * 8;
  const int ldst = wid * 1024;

  gload16(gA,            lds + ldst);
  gload16(gA + 64 * DIM, lds + 4096 + ldst);
  gload16(gB,            lds + 8192 + ldst);
  gload16(gB + 64 * DIM, lds + 12288 + ldst);
  __syncthreads();

  const int sw = (l15 >> 1) & 3;
  for (int kt = 0; kt < DIM / 32; ++kt) {
    char* cur = lds + (kt & 1) * 16384;
    if (kt + 1 < DIM / 32) {
      char* nxt = lds + ((kt + 1) & 1) * 16384;
      const f16* ga = gA + (kt + 1) * 32;
      const f16* gb = gB + (kt + 1) * 32;
      gload16(ga,            nxt + ldst);
      gload16(ga + 64 * DIM, nxt + 4096 + ldst);
      gload16(gb,            nxt + 8192 + ldst);
      gload16(gb + 64 * DIM, nxt + 12288 + ldst);
    }
    f16x8 af[4], bf[4];
#pragma unroll
    for (int mt = 0; mt < 4; ++mt)
      af[mt] = *(const f16x8*)(cur + (wm + mt * 16 + l15) * 64 + (l4 ^ sw) * 16);
#pragma unroll
    for (int nt = 0; nt < 4; ++nt)
      bf[nt] = *(const f16x8*)(cur + 8192 + (wn + nt * 16 + l15) * 64 + (l4 ^ sw) * 16);
#pragma unroll
    for (int mt = 0; mt < 4; ++mt)
#pragma unroll
      for (int nt = 0; nt < 4; ++nt)
        acc[mt][nt] = __builtin_amdgcn_mfma_f32_16x16x32_f16(af[mt], bf[nt], acc[mt][nt], 0, 0, 0);
    __syncthreads();
  }
}

// Fragment-native addresses (elements) within one (batch,head) panel:
//  Q/K: tile32 = s>>5 ; addr = tile32*2048 + (d>>4)*512 + ((d>>3)&1)*256 + (s&31)*8 + (d&7)
//  V:   tile64 = s>>6 ; addr = tile64*4096 + (d>>5)*2048 + ((s>>4)&3)*512 + ((s>>3)&1)*256 + (d&31)*8 + (s&7)

// ---------------- batched QKV projection (f16 inputs) ----------------
__global__ __launch_bounds__(256) void proj_kernel(
    const f16* __restrict__ Xq, const f16* __restrict__ Xk, const f16* __restrict__ Xv,
    const f16* __restrict__ Wt,
    const float* __restrict__ bq, const float* __restrict__ bk, const float* __restrict__ bv,
    f16* __restrict__ Q, f16* __restrict__ Kh, f16* __restrict__ Vt) {
  __shared__ __align__(16) char lds[32768];
  const int m0 = blockIdx.x * 128, n0 = blockIdx.y * 128;
  const int z = blockIdx.z;
  const f16* X = z == 0 ? Xq : z == 1 ? Xk : Xv;
  const f16* W = Wt + (size_t)z * DIM * DIM;
  const float* bias = z == 0 ? bq : z == 1 ? bk : bv;
  f32x4 acc[4][4] = {};
  gemm_core_sw(X + (size_t)m0 * DIM, W + (size_t)n0 * DIM, lds, acc);

  const int tid = threadIdx.x, wid = tid >> 6, lane = tid & 63;
  const int l15 = lane & 15, l4 = lane >> 4;
  const int wm = (wid >> 1) * 64, wn = (wid & 1) * 64;
#pragma unroll
  for (int nt = 0; nt < 4; ++nt) {
    const int col = n0 + wn + nt * 16 + l15;
    const float bb = bias[col];
    const int hh = col >> 6, d = col & 63;
#pragma unroll
    for (int mt = 0; mt < 4; ++mt)
#pragma unroll
      for (int j = 0; j < 4; ++j) {
        const int row = m0 + wm + mt * 16 + l4 * 4 + j;
        const float v = acc[mt][nt][j] + bb;
        const int n = row >> 11, s = row & (S_LEN - 1);
        const size_t panel = (size_t)(n * NHEAD + hh);
        if (z == 0) {
          const size_t a = panel * (S_LEN * HDIM) + (size_t)(s >> 5) * 2048 +
                           (d >> 4) * 512 + ((d >> 3) & 1) * 256 + (s & 31) * 8 + (d & 7);
          Q[a] = (f16)(v * QSCALE);
        } else if (z == 1) {
          const size_t a = panel * (S_LEN * HDIM) + (size_t)(s >> 5) * 2048 +
                           (d >> 4) * 512 + ((d >> 3) & 1) * 256 + (s & 31) * 8 + (d & 7);
          Kh[a] = (f16)v;
        } else {
          const size_t a = panel * (S_LEN * HDIM) + (size_t)(s >> 6) * 4096 +
                           (d >> 5) * 2048 + ((s >> 4) & 3) * 512 + ((s >> 3) & 1) * 256 +
                           (d & 31) * 8 + (s & 7);
          Vt[a] = (f16)v;
        }
      }
  }
}

// ------- 64x128 f16 GEMM core (outproj) -------
__device__ __forceinline__ void gemm_core_sw64(const f16* __restrict__ A, const f16* __restrict__ B,
                                               char* lds, f32x4 acc[2][4]) {
  const int tid = threadIdx.x;
  const int wid = tid >> 6, lane = tid & 63;
  const int l15 = lane & 15, l4 = lane >> 4;
  const int wm = (wid >> 1) * 32, wn = (wid & 1) * 64;
  const int rr = tid >> 2, cc = tid & 3;
  const int ccs = cc ^ ((rr >> 1) & 3);                    // pre-swizzled source slot
  const f16* gA = A + (size_t)rr * DIM + ccs * 8;          // rows 0..63
  const f16* gB = B + (size_t)rr * DIM + ccs * 8;
  const int ldst = wid * 1024;

  gload16(gA,            lds + ldst);                      // A rows 0..63
  gload16(gB,            lds + 4096 + ldst);               // B rows 0..63
  gload16(gB + 64 * DIM, lds + 8192 + ldst);               // B rows 64..127
  __syncthreads();

  const int sw = (l15 >> 1) & 3;
  for (int kt = 0; kt < DIM / 32; ++kt) {
    char* cur = lds + (kt & 1) * 12288;
    if (kt + 1 < DIM / 32) {
      char* nxt = lds + ((kt + 1) & 1) * 12288;
      const f16* ga = gA + (kt + 1) * 32;
      const f16* gb = gB + (kt + 1) * 32;
      gload16(ga,            nxt + ldst);
      gload16(gb,            nxt + 4096 + ldst);
      gload16(gb + 64 * DIM, nxt + 8192 + ldst);
    }
    f16x8 af[2], bf[4];
#pragma unroll
    for (int mt = 0; mt < 2; ++mt)
      af[mt] = *(const f16x8*)(cur + (wm + mt * 16 + l15) * 64 + (l4 ^ sw) * 16);
#pragma unroll
    for (int nt = 0; nt < 4; ++nt)
      bf[nt] = *(const f16x8*)(cur + 4096 + (wn + nt * 16 + l15) * 64 + (l4 ^ sw) * 16);
#pragma unroll
    for (int mt = 0; mt < 2; ++mt)
#pragma unroll
      for (int nt = 0; nt < 4; ++nt)
        acc[mt][nt] = __builtin_amdgcn_mfma_f32_16x16x32_f16(af[mt], bf[nt], acc[mt][nt], 0, 0, 0);
    __syncthreads();
  }
}

// ---------------- output projection -> fp32 d_out (64-row tile, XCD-chunked) --------
// 16m x 4n chunks per XCD: A-panels stay exclusive (local), W fetched 4x less.
__global__ __launch_bounds__(256) void outproj_kernel(
    const f16* __restrict__ A, const f16* __restrict__ Wt,
    const float* __restrict__ bias, float* __restrict__ Out) {
  __shared__ __align__(16) char lds[24576];
  const int fid = (int)blockIdx.x;                 // 0..511 linear
  const int c = fid >> 6, i = fid & 63;            // chunk (XCD), index-in-chunk
  const int mt_ = (i & 15) + (c >> 1) * 16;        // 0..63
  const int nt_ = ((i >> 4) & 3) + (c & 1) * 4;    // 0..7
  const int m0 = mt_ * 64, n0 = nt_ * 128;
  f32x4 acc[2][4] = {};
  gemm_core_sw64(A + (size_t)m0 * DIM, Wt + (size_t)n0 * DIM, lds, acc);

  const int tid = threadIdx.x, wid = tid >> 6, lane = tid & 63;
  const int l15 = lane & 15, l4 = lane >> 4;
  const int wm = (wid >> 1) * 32, wn = (wid & 1) * 64;
#pragma unroll
  for (int nt = 0; nt < 4; ++nt) {
    const int col = n0 + wn + nt * 16 + l15;
    const float bb = bias[col];
#pragma unroll
    for (int mt = 0; mt < 2; ++mt)
#pragma unroll
      for (int j = 0; j < 4; ++j) {
        const int row = m0 + wm + mt * 16 + l4 * 4 + j;
        Out[(size_t)row * DIM + col] = acc[mt][nt][j] + bb;
      }
  }
}

// -------- flash attention (r16 best): reg-staged async-split (T14) + XCD swizzle (T1) --------
__global__ __launch_bounds__(256, 2) void attn_kernel(
    const f16* __restrict__ Q, const f16* __restrict__ K,
    const f16* __restrict__ Vt, f16* __restrict__ AO) {
  const int bid = blockIdx.x;
  const int sbid = (bid & 7) * 64 + (bid >> 3);    // bijective: 512 % 8 == 0
  const int qt = sbid & 15, h = (sbid >> 4) & 15, b = sbid >> 8;
  const int tid = threadIdx.x;
  const int lane = tid & 63, wid = tid >> 6;
  const int l31 = lane & 31, hi = lane >> 5;

  __shared__ __align__(16) char kv_lds[2][16384];  // [buf][K 8KB | V 8KB]

  const int q0 = qt * 128 + wid * 32;
  const size_t panel = (size_t)(b * NHEAD + h) * (S_LEN * HDIM);
  const f16* Qp = Q + panel + (size_t)(q0 >> 5) * 2048;
  const char* KpB = (const char*)(K + panel);
  const char* VpB = (const char*)(Vt + panel);

  f16x8 qf[4];
#pragma unroll
  for (int sk = 0; sk < 4; ++sk)
    qf[sk] = *(const f16x8*)(Qp + sk * 512 + hi * 256 + l31 * 8);

  f32x16 accO[2] = {};            // O^T[d][q]: dt in {0,1}, col=q=l31
  float lacc0 = 0.f, lacc1 = 0.f, lacc2 = 0.f, lacc3 = 0.f;

  auto LOADR = [&](int it, f32x4 (&R)[4]) {
    const char* gK = KpB + (size_t)it * 8192 + tid * 16;
    const char* gV = VpB + (size_t)it * 8192 + tid * 16;
    R[0] = *(const f32x4*)(gK);
    R[1] = *(const f32x4*)(gK + 4096);
    R[2] = *(const f32x4*)(gV);
    R[3] = *(const f32x4*)(gV + 4096);
  };
  auto WRITER = [&](const f32x4 (&R)[4], int buf) {
    char* p = &kv_lds[buf][(tid >> 6) * 1024 + (tid & 63) * 16];
    *(f32x4*)(p)         = R[0];
    *(f32x4*)(p + 4096)  = R[1];
    *(f32x4*)(p + 8192)  = R[2];
    *(f32x4*)(p + 12288) = R[3];
  };

  auto QK = [&](int buf, f32x16 (&st)[2]) {
    const char* lk = &kv_lds[buf][0];
    f16x8 kf[2][4];
#pragma unroll
    for (int tt = 0; tt < 2; ++tt)
#pragma unroll
      for (int sk = 0; sk < 4; ++sk)
        kf[tt][sk] = *(const f16x8*)(lk + tt * 4096 + sk * 1024 + lane * 16);
    __builtin_amdgcn_s_setprio(1);
#pragma unroll
    for (int tt = 0; tt < 2; ++tt) {
      st[tt] = (f32x16)(0.f);
#pragma unroll
      for (int sk = 0; sk < 4; ++sk)
        st[tt] = __builtin_amdgcn_mfma_f32_32x32x16_f16(kf[tt][sk], qf[sk], st[tt], 0, 0, 0);
    }
    __builtin_amdgcn_s_setprio(0);
  };

  auto PHASE = [&](f32x16 (&st)[2], int buf) {
    const char* lv = &kv_lds[buf][8192];
    f16x8 vf[2][4];
#pragma unroll
    for (int dt = 0; dt < 2; ++dt)
#pragma unroll
      for (int s = 0; s < 4; ++s)
        vf[dt][s] = *(const f16x8*)(lv + dt * 4096 + s * 1024 + lane * 16);

    u32 pk[2][8];
#pragma unroll
    for (int tt = 0; tt < 2; ++tt)
#pragma unroll
      for (int j = 0; j < 8; ++j) {
        const float p0 = fast_exp2(st[tt][2 * j]);
        const float p1 = fast_exp2(st[tt][2 * j + 1]);
        const float ps = p0 + p1;
        if (((tt * 8 + j) & 3) == 0) lacc0 += ps;
        else if (((tt * 8 + j) & 3) == 1) lacc1 += ps;
        else if (((tt * 8 + j) & 3) == 2) lacc2 += ps;
        else lacc3 += ps;
        union { hf16x2 h; u32 w; } cv;
        cv.h = __builtin_amdgcn_cvt_pkrtz(p0, p1);
        pk[tt][j] = cv.w;
      }

    __builtin_amdgcn_s_setprio(1);
#pragma unroll
    for (int s = 0; s < 4; ++s) {
      const int tt = s >> 1, sl = s & 1;
      u32 w0 = pk[tt][4 * sl + 0], w2 = pk[tt][4 * sl + 2];
      u32 w1 = pk[tt][4 * sl + 1], w3 = pk[tt][4 * sl + 3];
      asm("v_permlane32_swap_b32 %0, %1" : "+v"(w0), "+v"(w2));
      asm("v_permlane32_swap_b32 %0, %1" : "+v"(w1), "+v"(w3));
      union { u32 w[4]; f16x8 v; } pf;
      pf.w[0] = w0; pf.w[1] = w1; pf.w[2] = w2; pf.w[3] = w3;
      accO[0] = __builtin_amdgcn_mfma_f32_32x32x16_f16(vf[0][s], pf.v, accO[0], 0, 0, 0);
      accO[1] = __builtin_amdgcn_mfma_f32_32x32x16_f16(vf[1][s], pf.v, accO[1], 0, 0, 0);
    }
    __builtin_amdgcn_s_setprio(0);
  };

  const int NIT = S_LEN / 64;  // 32 (even)

  f32x4 RA[4], RB[4];
  f32x16 st[2];
  LOADR(0, RA);
  WRITER(RA, 0);               // compiler waits RA's vmcnt here (prologue only)
  LOADR(1, RB);                // in flight across the first barrier
  SYNCL();

  for (int it = 0; it < NIT; it += 2) {
    if (it + 2 < NIT) LOADR(it + 2, RA);
    QK(0, st);
    PHASE(st, 0);
    WRITER(RB, 1);             // vmcnt wait auto-inserted for RB only
    SYNCL();
    if (it + 3 < NIT) LOADR(it + 3, RB);
    QK(1, st);
    PHASE(st, 1);
    if (it + 2 < NIT) WRITER(RA, 0);
    SYNCL();
  }

  const float l_loc = (lacc0 + lacc1) + (lacc2 + lacc3);
  const float l_all = l_loc + __shfl_xor(l_loc, 32);
  const float inv = 1.f / l_all;
  f16* aop = AO + ((size_t)(b * S_LEN + q0 + l31)) * DIM + h * HDIM;
#pragma unroll
  for (int dt = 0; dt < 2; ++dt)
#pragma unroll
    for (int j = 0; j < 8; ++j) {
      union { f16x2 h; u32 w; } cv;
      cv.h[0] = (f16)(accO[dt][2 * j] * inv);
      cv.h[1] = (f16)(accO[dt][2 * j + 1] * inv);
      const int d = ((2 * j) & 3) + 8 * ((2 * j) >> 2) + 4 * hi + dt * 32;
      *(f16x2*)(aop + d) = cv.h;
    }
}

extern "C" void kernel_launch(void* const* d_in, const int* in_sizes, int n_in,
                              void* d_out, int out_size, void* d_ws, size_t ws_size,
                              hipStream_t stream) {
  (void)in_sizes; (void)n_in; (void)out_size; (void)ws_size;
  const float* q  = (const float*)d_in[0];
  const float* k  = (const float*)d_in[1];
  const float* v  = (const float*)d_in[2];
  const float* Wq = (const float*)d_in[3];
  const float* bq = (const float*)d_in[4];
  const float* Wk = (const float*)d_in[5];
  const float* bk = (const float*)d_in[6];
  const float* Wv = (const float*)d_in[7];
  const float* bv = (const float*)d_in[8];
  const float* Wp = (const float*)d_in[9];
  const float* bp = (const float*)d_in[10];

  char* ws = (char*)d_ws;
  f16* Xq  = (f16*)(ws + OFF_XQ);
  f16* Xk  = (f16*)(ws + OFF_XK);
  f16* Xv  = (f16*)(ws + OFF_XV);
  f16* Wt  = (f16*)(ws + OFF_WT);
  f16* Qs  = (f16*)(ws + OFF_Q);
  f16* Kh  = (f16*)(ws + OFF_K);
  f16* Vts = (f16*)(ws + OFF_VT);
  f16* AO  = (f16*)(ws + OFF_AO);

  prep_kernel<<<dim3(2048, 4, 1), 256, 0, stream>>>(q, k, v, Wq, Wk, Wv, Wp, Xq, Xk, Xv, Wt);
  proj_kernel<<<dim3(32, 8, 3), 256, 0, stream>>>(Xq, Xk, Xv, Wt, bq, bk, bv, Qs, Kh, Vts);
  attn_kernel<<<dim3(512, 1, 1), 256, 0, stream>>>(Qs, Kh, Vts, AO);
  outproj_kernel<<<dim3(512, 1, 1), 256, 0, stream>>>(AO, Wt + 3ull * DIM * DIM, bp, (float*)d_out);
}